// Round 3
// baseline (1046.205 us; speedup 1.0000x reference)
//
#include <hip/hip_runtime.h>

typedef unsigned short u16;
typedef __bf16 bf16x8 __attribute__((ext_vector_type(8)));
typedef float f32x4 __attribute__((ext_vector_type(4)));

#define NSENT 40
#define SLEN 30
#define QLEN 20
#define ALEN 12
#define SCTX 2560

__device__ __forceinline__ float b2f(u16 u){ union{float f; unsigned i;} v; v.i = ((unsigned)u)<<16; return v.f; }
__device__ __forceinline__ u16 f2b(float f){ union{float f; unsigned u;} v; v.f=f; unsigned u=v.u; u += ((u>>16)&1u) + 0x7fffu; return (u16)(u>>16); }
__device__ __forceinline__ float sigm(float x){ return __builtin_amdgcn_rcpf(1.f + __expf(-x)); }
__device__ __forceinline__ float tanh_(float x){
  float a = fminf(fmaxf(2.f*x, -30.f), 30.f);
  float e = __expf(a);
  return 1.f - 2.f*__builtin_amdgcn_rcpf(e + 1.f);
}
__device__ __forceinline__ f32x4 mfma16(bf16x8 a, bf16x8 b, f32x4 c){
  return __builtin_amdgcn_mfma_f32_16x16x32_bf16(a, b, c, 0, 0, 0);
}

// ---------------------------------------------------------------------------
// Convert 10 [768x256] weight matrices + gate_W1 [256x1792] fp32 -> bf16.
// ---------------------------------------------------------------------------
__global__ void k_prep(
    const float* s0,const float* s1,const float* s2,const float* s3,const float* s4,
    const float* s5,const float* s6,const float* s7,const float* s8,const float* s9,
    const float* s10,
    u16* d0,u16* d1,u16* d2,u16* d3,u16* d4,u16* d5,u16* d6,u16* d7,u16* d8,u16* d9,u16* d10)
{
  int i = blockIdx.x*512 + threadIdx.x;   // 4736*512 = 2,424,832
  const float* s; u16* d; int off;
  if (i < 1966080){
    int seg = i/196608; off = i - seg*196608;
    switch(seg){
      case 0: s=s0; d=d0; break;  case 1: s=s1; d=d1; break;
      case 2: s=s2; d=d2; break;  case 3: s=s3; d=d3; break;
      case 4: s=s4; d=d4; break;  case 5: s=s5; d=d5; break;
      case 6: s=s6; d=d6; break;  case 7: s=s7; d=d7; break;
      case 8: s=s8; d=d8; break;  default: s=s9; d=d9; break;
    }
  } else { s=s10; d=d10; off = i - 1966080; }
  d[off] = f2b(s[off]);
}

// ---------------------------------------------------------------------------
// x-projections for all 4 GRUs: gi[row] = embed[tok] @ Wih^T + bih, bf16 out.
// M=32 rows/WG, N=768, K=256.  Rows: ctx 76800 | q 1280 | a1 768 | a2 768.
// ---------------------------------------------------------------------------
__global__ __launch_bounds__(512, 2) void k_xproj(
    const int* c_p, const int* q_p, const int* a1p, const int* a2p,
    const float* embed,
    const u16* cWihB, const u16* qWihB, const u16* aWihB,
    const float* cbih, const float* qbih, const float* abih,
    u16* gi_c, u16* gi_q, u16* gi_a1, u16* gi_a2)
{
  __shared__ u16 xb[32][264];
  __shared__ u16 go[32][776];
  int bid=blockIdx.x, tid=threadIdx.x;
  const int* toks; const u16* W; const float* bias; u16* out; int rl;
  if (bid < 2400){ toks=c_p; W=cWihB; bias=cbih; out=gi_c; rl=bid*32; }
  else if (bid < 2440){ toks=q_p; W=qWihB; bias=qbih; out=gi_q; rl=(bid-2400)*32; }
  else if (bid < 2464){ toks=a1p; W=aWihB; bias=abih; out=gi_a1; rl=(bid-2440)*32; }
  else               { toks=a2p; W=aWihB; bias=abih; out=gi_a2; rl=(bid-2464)*32; }
  #pragma unroll
  for (int p=0;p<4;p++){
    int i=p*512+tid; int row=i>>6, f4=i&63;
    int tok = toks[rl+row];
    float4 v = *((const float4*)(embed + (long)tok*256) + f4);
    u16* dst = &xb[row][f4*4];
    dst[0]=f2b(v.x); dst[1]=f2b(v.y); dst[2]=f2b(v.z); dst[3]=f2b(v.w);
  }
  const int w=tid>>6, lane=tid&63, c=lane&15, quad=lane>>4;
  f32x4 acc[2][6];
  #pragma unroll
  for (int Mt=0;Mt<2;Mt++)
    #pragma unroll
    for (int nt=0;nt<6;nt++) acc[Mt][nt]=(f32x4){0.f,0.f,0.f,0.f};
  __syncthreads();
  #pragma unroll
  for (int Kt=0;Kt<8;Kt++){
    bf16x8 a0 = *(const bf16x8*)&xb[c][Kt*32+quad*8];
    bf16x8 a1 = *(const bf16x8*)&xb[16+c][Kt*32+quad*8];
    #pragma unroll
    for (int nt=0;nt<6;nt++){
      bf16x8 bfr = *(const bf16x8*)(W + ((w*6+nt)*16+c)*256 + Kt*32 + quad*8);
      acc[0][nt]=mfma16(a0,bfr,acc[0][nt]);
      acc[1][nt]=mfma16(a1,bfr,acc[1][nt]);
    }
  }
  float biasv[6];
  #pragma unroll
  for (int nt=0;nt<6;nt++) biasv[nt]=bias[(w*6+nt)*16+c];
  #pragma unroll
  for (int Mt=0;Mt<2;Mt++)
    #pragma unroll
    for (int nt=0;nt<6;nt++)
      #pragma unroll
      for (int r=0;r<4;r++)
        go[Mt*16+quad*4+r][(w*6+nt)*16+c]=f2b(acc[Mt][nt][r]+biasv[nt]);
  __syncthreads();
  #pragma unroll
  for (int p=0;p<6;p++){
    int idx=p*512+tid;                 // 3072 = 32*96 uint4
    int row=idx/96, ch=idx-row*96;
    *(uint4*)(out + (long)(rl+row)*768 + ch*8) = *(uint4*)((char*)&go[row][0] + ch*16);
  }
}

// ---------------------------------------------------------------------------
// Recurrent encoder scans: Whh VGPR-resident (breg[48]); h fp32 master +
// bf16 hi/lo split MFMA A-operand.  172 WGs x 16 seqs.
// 0..159: ctx -> enc hi/lo; 160..163: q; 164..167: a1; 168..171: a2 (fp32 out)
// ---------------------------------------------------------------------------
__global__ __launch_bounds__(512, 2) void k_enc_scan(
    const int* c_mask, const int* q_mask, const int* a1m, const int* a2m,
    const u16* cWhhB, const u16* qWhhB, const u16* aWhhB,
    const float* cbhh, const float* qbhh, const float* abhh,
    const u16* gi_c, const u16* gi_q, const u16* gi_a1, const u16* gi_a2,
    u16* enc_hi, u16* enc_lo, float* enc_qf, float* enc_a1f, float* enc_a2f)
{
  __shared__ u16 hhi[16][264];
  __shared__ u16 hlo[16][264];
  __shared__ float gh[16][772];
  __shared__ float holdf[16][256];
  __shared__ float bhl[768];
  __shared__ int idxs[16];
  int bid=blockIdx.x, tid=threadIdx.x;
  const int* msk; const u16* W; const float* bhh; const u16* gi; int T, seq0, mode;
  u16 *ohi=0, *olo=0; float* of=0;
  if (bid<160){ msk=c_mask; W=cWhhB; bhh=cbhh; gi=gi_c; T=SLEN; seq0=bid*16; mode=0; ohi=enc_hi; olo=enc_lo; }
  else if (bid<164){ msk=q_mask; W=qWhhB; bhh=qbhh; gi=gi_q; T=QLEN; seq0=(bid-160)*16; mode=1; of=enc_qf; }
  else if (bid<168){ msk=a1m; W=aWhhB; bhh=abhh; gi=gi_a1; T=ALEN; seq0=(bid-164)*16; mode=1; of=enc_a1f; }
  else             { msk=a2m; W=aWhhB; bhh=abhh; gi=gi_a2; T=ALEN; seq0=(bid-168)*16; mode=1; of=enc_a2f; }
  if (tid<16){
    int len=0; const int* mr=msk+(seq0+tid)*T;
    for (int t=0;t<T;t++) len += (mr[t]==0);
    int id=len-1; if(id<0)id=0; if(id>T-1)id=T-1; idxs[tid]=id;
  }
  for (int i=tid;i<16*264;i+=512){ ((u16*)hhi)[i]=0; ((u16*)hlo)[i]=0; }
  for (int i=tid;i<16*256;i+=512) ((float*)holdf)[i]=0.f;
  for (int i=tid;i<768;i+=512) bhl[i]=bhh[i];
  const int w=tid>>6, lane=tid&63, c=lane&15, quad=lane>>4;
  uint4 breg[48];
  #pragma unroll
  for (int nt=0;nt<6;nt++)
    #pragma unroll
    for (int Kt=0;Kt<8;Kt++)
      breg[nt*8+Kt] = *(const uint4*)(W + ((w*6+nt)*16+c)*256 + Kt*32 + quad*8);
  __syncthreads();

  for (int t=0;t<T;t++){
    f32x4 acc[6];
    #pragma unroll
    for (int nt=0;nt<6;nt++) acc[nt]=(f32x4){0.f,0.f,0.f,0.f};
    #pragma unroll
    for (int Kt=0;Kt<8;Kt++){
      bf16x8 a=*(const bf16x8*)&hhi[c][Kt*32+quad*8];
      #pragma unroll
      for (int nt=0;nt<6;nt++) acc[nt]=mfma16(a,*(const bf16x8*)&breg[nt*8+Kt],acc[nt]);
    }
    #pragma unroll
    for (int Kt=0;Kt<8;Kt++){
      bf16x8 a=*(const bf16x8*)&hlo[c][Kt*32+quad*8];
      #pragma unroll
      for (int nt=0;nt<6;nt++) acc[nt]=mfma16(a,*(const bf16x8*)&breg[nt*8+Kt],acc[nt]);
    }
    #pragma unroll
    for (int nt=0;nt<6;nt++)
      #pragma unroll
      for (int r=0;r<4;r++)
        gh[quad*4+r][(w*6+nt)*16+c]=acc[nt][r];
    __syncthreads();
    #pragma unroll
    for (int p=0;p<8;p++){
      int uid=p*512+tid; int m=uid>>8, j=uid&255;
      long grow=(long)(seq0+m)*T+t;
      const u16* gr = gi + grow*768;
      float ir=b2f(gr[j]), iz=b2f(gr[256+j]), in_=b2f(gr[512+j]);
      float hr=gh[m][j]+bhl[j], hz=gh[m][256+j]+bhl[256+j], hn=gh[m][512+j]+bhl[512+j];
      float rr=sigm(ir+hr), zz=sigm(iz+hz);
      float nn=tanh_(in_+rr*hn);
      float ho=holdf[m][j];
      float hnew=(1.f-zz)*nn+zz*ho;
      holdf[m][j]=hnew;
      u16 hi=f2b(hnew); float lof=hnew-b2f(hi); u16 lo=f2b(lof);
      hhi[m][j]=hi; hlo[m][j]=lo;
      if (t==idxs[m]){
        long o=(long)(seq0+m)*256+j;
        if (mode==0){ ohi[o]=hi; olo[o]=lo; }
        else of[o]=hnew;
      }
    }
    __syncthreads();
  }
}

// ---------------------------------------------------------------------------
// gi_attn = enc_ctx(hi+lo) @ attn_Wih^T + attn_bih, fp32 out.  WG 40: mem=q.
// ---------------------------------------------------------------------------
__global__ __launch_bounds__(512, 2) void k_gi(
    const u16* enc_hi, const u16* enc_lo, const u16* tWihB, const float* tbih,
    float* gi_attn, const float* enc_qf, float* mem_f)
{
  int bid=blockIdx.x, tid=threadIdx.x;
  if (bid==40){ for (int i=tid;i<64*256;i+=512) mem_f[i]=enc_qf[i]; return; }
  __shared__ u16 ahi[64][264];
  __shared__ u16 alo[64][264];
  int seq0=bid*64;
  #pragma unroll
  for (int p=0;p<4;p++){
    int i=p*512+tid; int row=i>>5, ch=i&31;
    *(uint4*)((char*)&ahi[row][0]+ch*16) = *((const uint4*)(enc_hi+(long)(seq0+row)*256)+ch);
    *(uint4*)((char*)&alo[row][0]+ch*16) = *((const uint4*)(enc_lo+(long)(seq0+row)*256)+ch);
  }
  const int w=tid>>6, lane=tid&63, c=lane&15, quad=lane>>4;
  f32x4 acc[4][6];
  #pragma unroll
  for (int Mt=0;Mt<4;Mt++)
    #pragma unroll
    for (int nt=0;nt<6;nt++) acc[Mt][nt]=(f32x4){0.f,0.f,0.f,0.f};
  __syncthreads();
  #pragma unroll
  for (int Kt=0;Kt<8;Kt++){
    bf16x8 a[4];
    #pragma unroll
    for (int Mt=0;Mt<4;Mt++) a[Mt]=*(const bf16x8*)&ahi[Mt*16+c][Kt*32+quad*8];
    #pragma unroll
    for (int nt=0;nt<6;nt++){
      bf16x8 bfr=*(const bf16x8*)(tWihB + ((w*6+nt)*16+c)*256 + Kt*32 + quad*8);
      #pragma unroll
      for (int Mt=0;Mt<4;Mt++) acc[Mt][nt]=mfma16(a[Mt],bfr,acc[Mt][nt]);
    }
  }
  #pragma unroll
  for (int Kt=0;Kt<8;Kt++){
    bf16x8 a[4];
    #pragma unroll
    for (int Mt=0;Mt<4;Mt++) a[Mt]=*(const bf16x8*)&alo[Mt*16+c][Kt*32+quad*8];
    #pragma unroll
    for (int nt=0;nt<6;nt++){
      bf16x8 bfr=*(const bf16x8*)(tWihB + ((w*6+nt)*16+c)*256 + Kt*32 + quad*8);
      #pragma unroll
      for (int Mt=0;Mt<4;Mt++) acc[Mt][nt]=mfma16(a[Mt],bfr,acc[Mt][nt]);
    }
  }
  #pragma unroll
  for (int nt=0;nt<6;nt++){
    float bv=tbih[(w*6+nt)*16+c];
    #pragma unroll
    for (int Mt=0;Mt<4;Mt++)
      #pragma unroll
      for (int r=0;r<4;r++)
        gi_attn[(long)(seq0+Mt*16+quad*4+r)*768 + (w*6+nt)*16+c] = acc[Mt][nt][r]+bv;
  }
}

// ---------------------------------------------------------------------------
// Gate: feat built on the fly (fp32 sources); g = sigmoid(tanh(feat@W1^T+b1)@W2^T+b2)
// ---------------------------------------------------------------------------
__global__ __launch_bounds__(512, 1) void k_gate(
    const u16* enc_hi, const u16* enc_lo, const float* mem_f, const float* enc_qf,
    const u16* W1, const float* b1, const float* W2, const float* b2, float* g)
{
  __shared__ float ctf[32][257];
  __shared__ float mvf[32][257];
  __shared__ float qvf[32][257];
  __shared__ u16 ab[32][264];
  __shared__ float pl[32][8];
  int bid=blockIdx.x, tid=threadIdx.x, seq0=bid*32;
  #pragma unroll
  for (int p=0;p<16;p++){
    int i=p*512+tid; int row=i>>8, j=i&255;
    int grow=seq0+row; int b=grow/NSENT;
    ctf[row][j]=b2f(enc_hi[(long)grow*256+j])+b2f(enc_lo[(long)grow*256+j]);
    mvf[row][j]=mem_f[b*256+j];
    qvf[row][j]=enc_qf[b*256+j];
  }
  const int w=tid>>6, lane=tid&63, c=lane&15, quad=lane>>4;
  f32x4 acc[2][2];
  float w2v[2];
  #pragma unroll
  for (int nt=0;nt<2;nt++){
    int n=(w*2+nt)*16+c;
    float bv=b1[n];
    acc[0][nt]=(f32x4){bv,bv,bv,bv}; acc[1][nt]=acc[0][nt];
    w2v[nt]=W2[n];
  }
  for (int ch=0; ch<7; ch++){
    __syncthreads();
    #pragma unroll
    for (int p=0;p<16;p++){
      int i=p*512+tid; int row=i>>8, j=i&255;
      float ct=ctf[row][j], mv=mvf[row][j], qv=qvf[row][j];
      float v;
      if      (ch==0) v=ct;
      else if (ch==1) v=mv;
      else if (ch==2) v=qv;
      else if (ch==3) v=ct*qv;
      else if (ch==4) v=ct*mv;
      else if (ch==5) v=fabsf(ct-qv);
      else            v=fabsf(ct-mv);
      ab[row][j]=f2b(v);
    }
    __syncthreads();
    #pragma unroll
    for (int Kt=0;Kt<8;Kt++){
      bf16x8 a0=*(const bf16x8*)&ab[c][Kt*32+quad*8];
      bf16x8 a1=*(const bf16x8*)&ab[16+c][Kt*32+quad*8];
      #pragma unroll
      for (int nt=0;nt<2;nt++){
        int n=(w*2+nt)*16+c;
        bf16x8 bfr=*(const bf16x8*)(W1 + (long)n*1792 + ch*256 + Kt*32 + quad*8);
        acc[0][nt]=mfma16(a0,bfr,acc[0][nt]);
        acc[1][nt]=mfma16(a1,bfr,acc[1][nt]);
      }
    }
  }
  float pm[8];
  #pragma unroll
  for (int i=0;i<8;i++){
    int Mt=i>>2, r=i&3;
    float s=0.f;
    #pragma unroll
    for (int nt=0;nt<2;nt++) s += tanh_(acc[Mt][nt][r])*w2v[nt];
    pm[i]=s;
  }
  #pragma unroll
  for (int off=1;off<16;off<<=1)
    #pragma unroll
    for (int i=0;i<8;i++) pm[i]+=__shfl_xor(pm[i],off,64);
  if (c==0){
    #pragma unroll
    for (int i=0;i<8;i++){ int m=(i>>2)*16+quad*4+(i&3); pl[m][w]=pm[i]; }
  }
  __syncthreads();
  if (tid<32){
    float s=b2[0];
    #pragma unroll
    for (int ww=0;ww<8;ww++) s+=pl[tid][ww];
    g[seq0+tid]=sigm(s);
  }
}

// ---------------------------------------------------------------------------
// Episodic scan (one episode): 16 WGs x 4 batch rows; attn_Whh in VGPRs;
// h fp32 master; gi_attn/g fp32; memory fp32 master + hi/lo split MFMA.
// ---------------------------------------------------------------------------
__global__ __launch_bounds__(512, 2) void k_scan(
    const u16* tWhhB, const float* tbhh,
    const float* gi_attn, const float* g,
    float* mem_f, const u16* mWihB, const u16* mWhhB,
    const float* mbih, const float* mbhh)
{
  __shared__ u16 hb[16][264];
  __shared__ u16 mhi[16][264];
  __shared__ u16 mlo[16][264];
  __shared__ float gh[4][772];
  __shared__ float gh2[4][772];
  __shared__ float holdf[4][256];
  __shared__ float memfl[4][256];
  __shared__ float bhl[768];
  int bid=blockIdx.x, tid=threadIdx.x, b0=bid*4;
  const int w=tid>>6, lane=tid&63, c=lane&15, quad=lane>>4;
  for (int i=tid;i<16*264;i+=512){ ((u16*)hb)[i]=0; ((u16*)mhi)[i]=0; ((u16*)mlo)[i]=0; }
  for (int i=tid;i<1024;i+=512){
    int m=i>>8, j=i&255;
    holdf[m][j]=0.f;
    float v=mem_f[(b0+m)*256+j]; memfl[m][j]=v;
    u16 hi=f2b(v); mhi[m][j]=hi; mlo[m][j]=f2b(v-b2f(hi));
  }
  for (int i=tid;i<768;i+=512) bhl[i]=tbhh[i];
  uint4 breg[48];
  #pragma unroll
  for (int nt=0;nt<6;nt++)
    #pragma unroll
    for (int Kt=0;Kt<8;Kt++)
      breg[nt*8+Kt] = *(const uint4*)(tWhhB + ((w*6+nt)*16+c)*256 + Kt*32 + quad*8);
  __syncthreads();

  for (int s=0;s<NSENT;s++){
    f32x4 acc[6];
    #pragma unroll
    for (int nt=0;nt<6;nt++) acc[nt]=(f32x4){0.f,0.f,0.f,0.f};
    #pragma unroll
    for (int Kt=0;Kt<8;Kt++){
      bf16x8 a=*(const bf16x8*)&hb[c][Kt*32+quad*8];
      #pragma unroll
      for (int nt=0;nt<6;nt++) acc[nt]=mfma16(a,*(const bf16x8*)&breg[nt*8+Kt],acc[nt]);
    }
    if (quad==0){
      #pragma unroll
      for (int nt=0;nt<6;nt++)
        #pragma unroll
        for (int r=0;r<4;r++)
          gh[r][(w*6+nt)*16+c]=acc[nt][r];
    }
    __syncthreads();
    #pragma unroll
    for (int p=0;p<2;p++){
      int uid=p*512+tid; int m=uid>>8, j=uid&255;
      int row=(b0+m)*NSENT+s;
      float gv=g[row];
      const float* gr=gi_attn+(long)row*768;
      float ir=gr[j], iz=gr[256+j], in_=gr[512+j];
      float hr=gh[m][j]+bhl[j], hz=gh[m][256+j]+bhl[256+j], hn=gh[m][512+j]+bhl[512+j];
      float rr=sigm(ir+hr), zz=sigm(iz+hz), nn=tanh_(in_+rr*hn);
      float ho=holdf[m][j];
      float hc=(1.f-zz)*nn+zz*ho;
      float hnew=gv*hc+(1.f-gv)*ho;
      holdf[m][j]=hnew;
      hb[m][j]=f2b(hnew);
    }
    __syncthreads();
  }
  // memory GRU: gi_m = e@mWih^T (+mbih), gh_m = mem(hi/lo)@mWhh^T (+mbhh)
  f32x4 ai[6], ah[6];
  #pragma unroll
  for (int nt=0;nt<6;nt++){ ai[nt]=(f32x4){0.f,0.f,0.f,0.f}; ah[nt]=ai[nt]; }
  #pragma unroll
  for (int Kt=0;Kt<8;Kt++){
    bf16x8 a=*(const bf16x8*)&hb[c][Kt*32+quad*8];
    #pragma unroll
    for (int nt=0;nt<6;nt++){
      bf16x8 bfr=*(const bf16x8*)(mWihB + ((w*6+nt)*16+c)*256 + Kt*32 + quad*8);
      ai[nt]=mfma16(a,bfr,ai[nt]);
    }
  }
  #pragma unroll
  for (int Kt=0;Kt<8;Kt++){
    bf16x8 a=*(const bf16x8*)&mhi[c][Kt*32+quad*8];
    #pragma unroll
    for (int nt=0;nt<6;nt++){
      bf16x8 bfr=*(const bf16x8*)(mWhhB + ((w*6+nt)*16+c)*256 + Kt*32 + quad*8);
      ah[nt]=mfma16(a,bfr,ah[nt]);
    }
  }
  #pragma unroll
  for (int Kt=0;Kt<8;Kt++){
    bf16x8 a=*(const bf16x8*)&mlo[c][Kt*32+quad*8];
    #pragma unroll
    for (int nt=0;nt<6;nt++){
      bf16x8 bfr=*(const bf16x8*)(mWhhB + ((w*6+nt)*16+c)*256 + Kt*32 + quad*8);
      ah[nt]=mfma16(a,bfr,ah[nt]);
    }
  }
  if (quad==0){
    #pragma unroll
    for (int nt=0;nt<6;nt++)
      #pragma unroll
      for (int r=0;r<4;r++){
        gh[r][(w*6+nt)*16+c]=ai[nt][r];
        gh2[r][(w*6+nt)*16+c]=ah[nt][r];
      }
  }
  __syncthreads();
  #pragma unroll
  for (int p=0;p<2;p++){
    int uid=p*512+tid; int m=uid>>8, j=uid&255;
    float ir=gh[m][j]+mbih[j], iz=gh[m][256+j]+mbih[256+j], in_=gh[m][512+j]+mbih[512+j];
    float hr=gh2[m][j]+mbhh[j], hz=gh2[m][256+j]+mbhh[256+j], hn=gh2[m][512+j]+mbhh[512+j];
    float rr=sigm(ir+hr), zz=sigm(iz+hz), nn=tanh_(in_+rr*hn);
    float mo=memfl[m][j];
    mem_f[(b0+m)*256+j]=(1.f-zz)*nn+zz*mo;
  }
}

// ---------------------------------------------------------------------------
// Final: softmax( tanh([mem|a1|a2] @ outW1^T + b1) @ outW2^T + b2 ), all fp32.
// ---------------------------------------------------------------------------
__global__ void k_final(const float* mem_f, const float* a1f, const float* a2f,
    const float* W1o, const float* b1o, const float* W2o, const float* b2o, float* outp)
{
  __shared__ float af[768];
  __shared__ float tl[256];
  __shared__ float lg[2];
  int b=blockIdx.x, tid=threadIdx.x;
  af[tid]     = mem_f[b*256+tid];
  af[256+tid] = a1f[b*256+tid];
  af[512+tid] = a2f[b*256+tid];
  __syncthreads();
  float s=b1o[tid];
  const float* wr=W1o + (long)tid*768;
  for (int k=0;k<768;k++) s += af[k]*wr[k];
  tl[tid]=tanh_(s);
  __syncthreads();
  if (tid<2){
    float l=b2o[tid];
    const float* w2=W2o + tid*256;
    for (int k=0;k<256;k++) l += tl[k]*w2[k];
    lg[tid]=l;
  }
  __syncthreads();
  if (tid==0){
    float m=fmaxf(lg[0],lg[1]);
    float e0=__expf(lg[0]-m), e1=__expf(lg[1]-m);
    float inv=1.f/(e0+e1);
    outp[b*2]=e0*inv; outp[b*2+1]=e1*inv;
  }
}

// ---------------------------------------------------------------------------
extern "C" void kernel_launch(void* const* d_in, const int* in_sizes, int n_in,
                              void* d_out, int out_size, void* d_ws, size_t ws_size,
                              hipStream_t stream) {
  const int* c_p   = (const int*)d_in[0];
  const int* c_m   = (const int*)d_in[1];
  const int* q_p   = (const int*)d_in[2];
  const int* q_m   = (const int*)d_in[3];
  const int* a1p   = (const int*)d_in[4];
  const int* a1m   = (const int*)d_in[5];
  const int* a2p   = (const int*)d_in[6];
  const int* a2m   = (const int*)d_in[7];
  const float* embed = (const float*)d_in[8];
  const float* cWih=(const float*)d_in[9],  *cWhh=(const float*)d_in[10], *cbih=(const float*)d_in[11], *cbhh=(const float*)d_in[12];
  const float* qWih=(const float*)d_in[13], *qWhh=(const float*)d_in[14], *qbih=(const float*)d_in[15], *qbhh=(const float*)d_in[16];
  const float* aWih=(const float*)d_in[17], *aWhh=(const float*)d_in[18], *abih=(const float*)d_in[19], *abhh=(const float*)d_in[20];
  const float* tWih=(const float*)d_in[21], *tWhh=(const float*)d_in[22], *tbih=(const float*)d_in[23], *tbhh=(const float*)d_in[24];
  const float* mWih=(const float*)d_in[25], *mWhh=(const float*)d_in[26], *mbih=(const float*)d_in[27], *mbhh=(const float*)d_in[28];
  const float* gW1=(const float*)d_in[29], *gb1=(const float*)d_in[30], *gW2=(const float*)d_in[31], *gb2=(const float*)d_in[32];
  const float* oW1=(const float*)d_in[33], *ob1=(const float*)d_in[34], *oW2=(const float*)d_in[35], *ob2=(const float*)d_in[36];

  char* ws = (char*)d_ws;
  size_t off = 0;
  u16* cWihB=(u16*)(ws+off); off+=393216;
  u16* cWhhB=(u16*)(ws+off); off+=393216;
  u16* qWihB=(u16*)(ws+off); off+=393216;
  u16* qWhhB=(u16*)(ws+off); off+=393216;
  u16* aWihB=(u16*)(ws+off); off+=393216;
  u16* aWhhB=(u16*)(ws+off); off+=393216;
  u16* tWihB=(u16*)(ws+off); off+=393216;
  u16* tWhhB=(u16*)(ws+off); off+=393216;
  u16* mWihB=(u16*)(ws+off); off+=393216;
  u16* mWhhB=(u16*)(ws+off); off+=393216;
  u16* gW1B =(u16*)(ws+off); off+=917504;
  u16* gi_c =(u16*)(ws+off); off+=(size_t)76800*768*2;
  u16* gi_q =(u16*)(ws+off); off+=(size_t)1280*768*2;
  u16* gi_a1=(u16*)(ws+off); off+=(size_t)768*768*2;
  u16* gi_a2=(u16*)(ws+off); off+=(size_t)768*768*2;
  u16* enc_hi=(u16*)(ws+off); off+=(size_t)SCTX*256*2;
  u16* enc_lo=(u16*)(ws+off); off+=(size_t)SCTX*256*2;
  float* enc_qf =(float*)(ws+off); off+=64*256*4;
  float* enc_a1f=(float*)(ws+off); off+=64*256*4;
  float* enc_a2f=(float*)(ws+off); off+=64*256*4;
  float* mem_f  =(float*)(ws+off); off+=64*256*4;
  float* gi_attn=(float*)(ws+off); off+=(size_t)SCTX*768*4;
  float* gbuf   =(float*)(ws+off); off+=SCTX*4;

  k_prep<<<4736, 512, 0, stream>>>(cWih,cWhh,qWih,qWhh,aWih,aWhh,tWih,tWhh,mWih,mWhh,gW1,
      cWihB,cWhhB,qWihB,qWhhB,aWihB,aWhhB,tWihB,tWhhB,mWihB,mWhhB,gW1B);

  k_xproj<<<2488, 512, 0, stream>>>(c_p,q_p,a1p,a2p, embed,
      cWihB,qWihB,aWihB, cbih,qbih,abih, gi_c,gi_q,gi_a1,gi_a2);

  k_enc_scan<<<172, 512, 0, stream>>>(c_m,q_m,a1m,a2m,
      cWhhB,qWhhB,aWhhB, cbhh,qbhh,abhh, gi_c,gi_q,gi_a1,gi_a2,
      enc_hi,enc_lo, enc_qf,enc_a1f,enc_a2f);

  k_gi<<<41, 512, 0, stream>>>(enc_hi,enc_lo, tWihB, tbih, gi_attn, enc_qf, mem_f);

  for (int ep=0; ep<3; ep++){
    k_gate<<<80, 512, 0, stream>>>(enc_hi,enc_lo, mem_f, enc_qf, gW1B, gb1, gW2, gb2, gbuf);
    k_scan<<<16, 512, 0, stream>>>(tWhhB, tbhh, gi_attn, gbuf, mem_f, mWihB, mWhhB, mbih, mbhh);
  }

  k_final<<<64, 256, 0, stream>>>(mem_f, enc_a1f, enc_a2f, oW1, ob1, oW2, ob2, (float*)d_out);
}

// Round 4
// 957.695 us; speedup vs baseline: 1.0924x; 1.0924x over previous
//
#include <hip/hip_runtime.h>

typedef unsigned short u16;
typedef __bf16 bf16x8 __attribute__((ext_vector_type(8)));
typedef float f32x4 __attribute__((ext_vector_type(4)));

#define NSENT 40
#define SLEN 30
#define QLEN 20
#define ALEN 12
#define SCTX 2560

__device__ __forceinline__ float b2f(u16 u){ union{float f; unsigned i;} v; v.i = ((unsigned)u)<<16; return v.f; }
__device__ __forceinline__ u16 f2b(float f){ union{float f; unsigned u;} v; v.f=f; unsigned u=v.u; u += ((u>>16)&1u) + 0x7fffu; return (u16)(u>>16); }
__device__ __forceinline__ float sigm(float x){ return __builtin_amdgcn_rcpf(1.f + __expf(-x)); }
__device__ __forceinline__ float tanh_(float x){
  float a = fminf(fmaxf(2.f*x, -30.f), 30.f);
  float e = __expf(a);
  return 1.f - 2.f*__builtin_amdgcn_rcpf(e + 1.f);
}
__device__ __forceinline__ f32x4 mfma16(bf16x8 a, bf16x8 b, f32x4 c){
  return __builtin_amdgcn_mfma_f32_16x16x32_bf16(a, b, c, 0, 0, 0);
}

// ---------------------------------------------------------------------------
// Prep. pi-permutation: n' = g16*48 + gate*16 + c  <->  j = gate*256 + g16*16 + c.
// 8 permuted bf16 mats (c/q/a/t ih+hh), 2 plain (mWih,mWhh), gW1 plain bf16,
// 8 permuted fp32 biases.
// ---------------------------------------------------------------------------
__global__ void k_prep(
    const float* cWih, const float* cWhh, const float* qWih, const float* qWhh,
    const float* aWih, const float* aWhh, const float* tWih, const float* tWhh,
    const float* mWih, const float* mWhh, const float* gW1,
    const float* cbih, const float* cbhh, const float* qbih, const float* qbhh,
    const float* abih, const float* abhh, const float* tbih, const float* tbhh,
    u16* P0,u16* P1,u16* P2,u16* P3,u16* P4,u16* P5,u16* P6,u16* P7,
    u16* PmWih, u16* PmWhh, u16* PgW1,
    float* B0,float* B1,float* B2,float* B3,float* B4,float* B5,float* B6,float* B7)
{
  int i = blockIdx.x*512 + threadIdx.x;     // grid 4748*512 = 2,430,976
  if (i < 1572864){
    int seg = i/196608; int e = i - seg*196608;
    int np = e>>8, k = e&255;
    int g16 = np/48, rem = np - g16*48, gate = rem>>4, cc = rem&15;
    int j = gate*256 + g16*16 + cc;
    const float* S;
    u16* D;
    switch(seg){
      case 0: S=cWih; D=P0; break; case 1: S=cWhh; D=P1; break;
      case 2: S=qWih; D=P2; break; case 3: S=qWhh; D=P3; break;
      case 4: S=aWih; D=P4; break; case 5: S=aWhh; D=P5; break;
      case 6: S=tWih; D=P6; break; default: S=tWhh; D=P7; break;
    }
    D[e] = f2b(S[j*256 + k]);
  } else if (i < 1966080){
    int e = i - 1572864;
    if (e < 196608) PmWih[e]=f2b(mWih[e]);
    else PmWhh[e-196608]=f2b(mWhh[e-196608]);
  } else if (i < 2424832){
    int e = i - 1966080;
    PgW1[e] = f2b(gW1[e]);
  } else {
    int e = i - 2424832;
    int seg = e/768; int np = e - seg*768;
    int g16 = np/48, rem = np - g16*48, gate = rem>>4, cc = rem&15;
    int j = gate*256 + g16*16 + cc;
    const float* S; float* D;
    switch(seg){
      case 0: S=cbih; D=B0; break; case 1: S=cbhh; D=B1; break;
      case 2: S=qbih; D=B2; break; case 3: S=qbhh; D=B3; break;
      case 4: S=abih; D=B4; break; case 5: S=abhh; D=B5; break;
      case 6: S=tbih; D=B6; break; default: S=tbhh; D=B7; break;
    }
    D[np] = S[j];
  }
}

// ---------------------------------------------------------------------------
// x-projections (pi-permuted cols): gi[row][n'] = (embed[tok] @ Wih'^T)[n'] + bih'[n'].
// ---------------------------------------------------------------------------
__global__ __launch_bounds__(512, 2) void k_xproj(
    const int* c_p, const int* q_p, const int* a1p, const int* a2p,
    const float* embed,
    const u16* cWihP, const u16* qWihP, const u16* aWihP,
    const float* cBih, const float* qBih, const float* aBih,
    u16* gi_c, u16* gi_q, u16* gi_a1, u16* gi_a2)
{
  __shared__ u16 xb[32][264];
  __shared__ u16 go[32][776];
  int bid=blockIdx.x, tid=threadIdx.x;
  const int* toks; const u16* W; const float* bias; u16* out; int rl;
  if (bid < 2400){ toks=c_p; W=cWihP; bias=cBih; out=gi_c; rl=bid*32; }
  else if (bid < 2440){ toks=q_p; W=qWihP; bias=qBih; out=gi_q; rl=(bid-2400)*32; }
  else if (bid < 2464){ toks=a1p; W=aWihP; bias=aBih; out=gi_a1; rl=(bid-2440)*32; }
  else               { toks=a2p; W=aWihP; bias=aBih; out=gi_a2; rl=(bid-2464)*32; }
  #pragma unroll
  for (int p=0;p<4;p++){
    int i=p*512+tid; int row=i>>6, f4=i&63;
    int tok = toks[rl+row];
    float4 v = *((const float4*)(embed + (long)tok*256) + f4);
    u16* dst = &xb[row][f4*4];
    dst[0]=f2b(v.x); dst[1]=f2b(v.y); dst[2]=f2b(v.z); dst[3]=f2b(v.w);
  }
  const int w=tid>>6, lane=tid&63, c=lane&15, quad=lane>>4;
  f32x4 acc[2][6];
  #pragma unroll
  for (int Mt=0;Mt<2;Mt++)
    #pragma unroll
    for (int nt=0;nt<6;nt++) acc[Mt][nt]=(f32x4){0.f,0.f,0.f,0.f};
  __syncthreads();
  #pragma unroll
  for (int Kt=0;Kt<8;Kt++){
    bf16x8 a0 = *(const bf16x8*)&xb[c][Kt*32+quad*8];
    bf16x8 a1 = *(const bf16x8*)&xb[16+c][Kt*32+quad*8];
    #pragma unroll
    for (int nt=0;nt<6;nt++){
      bf16x8 bfr = *(const bf16x8*)(cWihP==W||qWihP==W||aWihP==W ?
                    W + ((w*6+nt)*16+c)*256 + Kt*32 + quad*8 :
                    W + ((w*6+nt)*16+c)*256 + Kt*32 + quad*8);
      acc[0][nt]=mfma16(a0,bfr,acc[0][nt]);
      acc[1][nt]=mfma16(a1,bfr,acc[1][nt]);
    }
  }
  float biasv[6];
  #pragma unroll
  for (int nt=0;nt<6;nt++) biasv[nt]=bias[(w*6+nt)*16+c];
  #pragma unroll
  for (int Mt=0;Mt<2;Mt++)
    #pragma unroll
    for (int nt=0;nt<6;nt++)
      #pragma unroll
      for (int r=0;r<4;r++)
        go[Mt*16+quad*4+r][(w*6+nt)*16+c]=f2b(acc[Mt][nt][r]+biasv[nt]);
  __syncthreads();
  #pragma unroll
  for (int p=0;p<6;p++){
    int idx=p*512+tid;
    int row=idx/96, ch=idx-row*96;
    *(uint4*)(out + (long)(rl+row)*768 + ch*8) = *(uint4*)((char*)&go[row][0] + ch*16);
  }
}

// ---------------------------------------------------------------------------
// Recurrent encoder scans, in-lane gates (pi layout), 1 barrier/step,
// double-buffered gi prefetch. 172 WGs x 16 seqs.
// ---------------------------------------------------------------------------
__global__ __launch_bounds__(512, 2) void k_enc_scan(
    const int* c_mask, const int* q_mask, const int* a1m, const int* a2m,
    const u16* cWhhP, const u16* qWhhP, const u16* aWhhP,
    const float* cBhh, const float* qBhh, const float* aBhh,
    const u16* gi_c, const u16* gi_q, const u16* gi_a1, const u16* gi_a2,
    u16* enc_hi, u16* enc_lo, float* enc_qf, float* enc_a1f, float* enc_a2f)
{
  __shared__ u16 hhi[16][264];
  __shared__ u16 hlo[16][264];
  __shared__ u16 gib[2][16][768];
  __shared__ int idxs[16];
  int bid=blockIdx.x, tid=threadIdx.x;
  const int* msk; const u16* W; const float* bhh; const u16* gi; int T, seq0, mode;
  u16 *ohi=0, *olo=0; float* of=0;
  if (bid<160){ msk=c_mask; W=cWhhP; bhh=cBhh; gi=gi_c; T=SLEN; seq0=bid*16; mode=0; ohi=enc_hi; olo=enc_lo; }
  else if (bid<164){ msk=q_mask; W=qWhhP; bhh=qBhh; gi=gi_q; T=QLEN; seq0=(bid-160)*16; mode=1; of=enc_qf; }
  else if (bid<168){ msk=a1m; W=aWhhP; bhh=aBhh; gi=gi_a1; T=ALEN; seq0=(bid-164)*16; mode=1; of=enc_a1f; }
  else             { msk=a2m; W=aWhhP; bhh=aBhh; gi=gi_a2; T=ALEN; seq0=(bid-168)*16; mode=1; of=enc_a2f; }
  if (tid<16){
    int len=0; const int* mr=msk+(seq0+tid)*T;
    for (int t=0;t<T;t++) len += (mr[t]==0);
    int id=len-1; if(id<0)id=0; if(id>T-1)id=T-1; idxs[tid]=id;
  }
  for (int i=tid;i<16*264;i+=512){ ((u16*)hhi)[i]=0; ((u16*)hlo)[i]=0; }
  const int w=tid>>6, lane=tid&63, c=lane&15, quad=lane>>4;
  float biasv[6];
  #pragma unroll
  for (int nt=0;nt<6;nt++) biasv[nt]=bhh[w*96+nt*16+c];
  uint4 breg[48];
  #pragma unroll
  for (int nt=0;nt<6;nt++)
    #pragma unroll
    for (int Kt=0;Kt<8;Kt++)
      breg[nt*8+Kt] = *(const uint4*)(W + (w*96+nt*16+c)*256 + Kt*32 + quad*8);
  float hreg[8];
  #pragma unroll
  for (int i=0;i<8;i++) hreg[i]=0.f;
  // staging pointers: idx = p*512+tid -> row=idx/96, 8-u16 chunk ch=idx%96
  const u16* gp[3];
  #pragma unroll
  for (int p=0;p<3;p++){
    int idx=p*512+tid; int row=idx/96, ch=idx-row*96;
    gp[p] = gi + ((long)(seq0+row)*T)*768 + ch*8;
  }
  u16* gf0 = &gib[0][0][0];
  u16* gf1 = &gib[1][0][0];
  {
    uint4 s0[3];
    #pragma unroll
    for (int p=0;p<3;p++) s0[p]=*(const uint4*)(gp[p]);
    #pragma unroll
    for (int p=0;p<3;p++) *(uint4*)(gf0 + (p*512+tid)*8) = s0[p];
  }
  __syncthreads();
  int cbuf=0;
  for (int t=0;t<T;t++){
    uint4 pre[3];
    bool pf = (t+1<T);
    if (pf){
      #pragma unroll
      for (int p=0;p<3;p++) pre[p]=*(const uint4*)(gp[p]+(long)(t+1)*768);
    }
    f32x4 acc[6];
    #pragma unroll
    for (int nt=0;nt<6;nt++) acc[nt]=(f32x4){0.f,0.f,0.f,0.f};
    #pragma unroll
    for (int Kt=0;Kt<8;Kt++){
      bf16x8 a=*(const bf16x8*)&hhi[c][Kt*32+quad*8];
      #pragma unroll
      for (int nt=0;nt<6;nt++) acc[nt]=mfma16(a,*(const bf16x8*)&breg[nt*8+Kt],acc[nt]);
    }
    #pragma unroll
    for (int Kt=0;Kt<8;Kt++){
      bf16x8 a=*(const bf16x8*)&hlo[c][Kt*32+quad*8];
      #pragma unroll
      for (int nt=0;nt<6;nt++) acc[nt]=mfma16(a,*(const bf16x8*)&breg[nt*8+Kt],acc[nt]);
    }
    if (pf){
      u16* gs = cbuf ? gf0 : gf1;
      #pragma unroll
      for (int p=0;p<3;p++) *(uint4*)(gs + (p*512+tid)*8) = pre[p];
    }
    const u16* gb = cbuf ? gf1 : gf0;
    #pragma unroll
    for (int r=0;r<4;r++){
      int m = quad*4+r;
      const u16* gr = gb + m*768 + w*96 + c;
      #pragma unroll
      for (int jj=0;jj<2;jj++){
        int j = w*32+jj*16+c;
        float ir = b2f(gr[jj*48]);
        float iz = b2f(gr[jj*48+16]);
        float in_= b2f(gr[jj*48+32]);
        float hr = acc[jj*3+0][r]+biasv[jj*3+0];
        float hz = acc[jj*3+1][r]+biasv[jj*3+1];
        float hn = acc[jj*3+2][r]+biasv[jj*3+2];
        float rr=sigm(ir+hr), zz=sigm(iz+hz), nn=tanh_(in_+rr*hn);
        float ho=hreg[r*2+jj];
        float hnew=(1.f-zz)*nn+zz*ho;
        hreg[r*2+jj]=hnew;
        u16 hi_=f2b(hnew); u16 lo_=f2b(hnew-b2f(hi_));
        hhi[m][j]=hi_; hlo[m][j]=lo_;
        if (t==idxs[m]){
          long o=(long)(seq0+m)*256+j;
          if (mode==0){ ohi[o]=hi_; olo[o]=lo_; }
          else of[o]=hnew;
        }
      }
    }
    __syncthreads();
    cbuf^=1;
  }
}

// ---------------------------------------------------------------------------
// gi_attn[row][n'] = enc_ctx(hi+lo) @ attn_Wih'^T + bih'  (fp32, pi cols).
// WG 40: mem = q.
// ---------------------------------------------------------------------------
__global__ __launch_bounds__(512, 2) void k_gi(
    const u16* enc_hi, const u16* enc_lo, const u16* tWihP, const float* tBih,
    float* gi_attn, const float* enc_qf, float* mem_f)
{
  int bid=blockIdx.x, tid=threadIdx.x;
  if (bid==40){ for (int i=tid;i<64*256;i+=512) mem_f[i]=enc_qf[i]; return; }
  __shared__ u16 ahi[64][264];
  __shared__ u16 alo[64][264];
  int seq0=bid*64;
  #pragma unroll
  for (int p=0;p<4;p++){
    int i=p*512+tid; int row=i>>5, ch=i&31;
    *(uint4*)((char*)&ahi[row][0]+ch*16) = *((const uint4*)(enc_hi+(long)(seq0+row)*256)+ch);
    *(uint4*)((char*)&alo[row][0]+ch*16) = *((const uint4*)(enc_lo+(long)(seq0+row)*256)+ch);
  }
  const int w=tid>>6, lane=tid&63, c=lane&15, quad=lane>>4;
  f32x4 acc[4][6];
  #pragma unroll
  for (int Mt=0;Mt<4;Mt++)
    #pragma unroll
    for (int nt=0;nt<6;nt++) acc[Mt][nt]=(f32x4){0.f,0.f,0.f,0.f};
  __syncthreads();
  #pragma unroll
  for (int Kt=0;Kt<8;Kt++){
    bf16x8 a[4];
    #pragma unroll
    for (int Mt=0;Mt<4;Mt++) a[Mt]=*(const bf16x8*)&ahi[Mt*16+c][Kt*32+quad*8];
    #pragma unroll
    for (int nt=0;nt<6;nt++){
      bf16x8 bfr=*(const bf16x8*)(tWihP + ((w*6+nt)*16+c)*256 + Kt*32 + quad*8);
      #pragma unroll
      for (int Mt=0;Mt<4;Mt++) acc[Mt][nt]=mfma16(a[Mt],bfr,acc[Mt][nt]);
    }
  }
  #pragma unroll
  for (int Kt=0;Kt<8;Kt++){
    bf16x8 a[4];
    #pragma unroll
    for (int Mt=0;Mt<4;Mt++) a[Mt]=*(const bf16x8*)&alo[Mt*16+c][Kt*32+quad*8];
    #pragma unroll
    for (int nt=0;nt<6;nt++){
      bf16x8 bfr=*(const bf16x8*)(tWihP + ((w*6+nt)*16+c)*256 + Kt*32 + quad*8);
      #pragma unroll
      for (int Mt=0;Mt<4;Mt++) acc[Mt][nt]=mfma16(a[Mt],bfr,acc[Mt][nt]);
    }
  }
  #pragma unroll
  for (int nt=0;nt<6;nt++){
    float bv=tBih[(w*6+nt)*16+c];
    #pragma unroll
    for (int Mt=0;Mt<4;Mt++)
      #pragma unroll
      for (int r=0;r<4;r++)
        gi_attn[(long)(seq0+Mt*16+quad*4+r)*768 + (w*6+nt)*16+c] = acc[Mt][nt][r]+bv;
  }
}

// ---------------------------------------------------------------------------
// Gate precompute: episode-invariant chunks {ct, q, ct*q, |ct-q|} -> partial.
// ---------------------------------------------------------------------------
__global__ __launch_bounds__(512, 1) void k_gatepre(
    const u16* enc_hi, const u16* enc_lo, const float* enc_qf,
    const u16* W1, const float* b1, float* partial)
{
  __shared__ float ctf[32][257];
  __shared__ float qvf[32][257];
  __shared__ u16 ab[32][264];
  int bid=blockIdx.x, tid=threadIdx.x, seq0=bid*32;
  #pragma unroll
  for (int p=0;p<16;p++){
    int i=p*512+tid; int row=i>>8, j=i&255;
    int grow=seq0+row; int b=grow/NSENT;
    ctf[row][j]=b2f(enc_hi[(long)grow*256+j])+b2f(enc_lo[(long)grow*256+j]);
    qvf[row][j]=enc_qf[b*256+j];
  }
  const int w=tid>>6, lane=tid&63, c=lane&15, quad=lane>>4;
  f32x4 acc[2][2];
  #pragma unroll
  for (int nt=0;nt<2;nt++){
    float bv=b1[(w*2+nt)*16+c];
    acc[0][nt]=(f32x4){bv,bv,bv,bv}; acc[1][nt]=acc[0][nt];
  }
  const int chl[4]={0,2,3,5};
  for (int ci=0; ci<4; ci++){
    int ch=chl[ci];
    __syncthreads();
    #pragma unroll
    for (int p=0;p<16;p++){
      int i=p*512+tid; int row=i>>8, j=i&255;
      float ct=ctf[row][j], qv=qvf[row][j];
      float v;
      if      (ch==0) v=ct;
      else if (ch==2) v=qv;
      else if (ch==3) v=ct*qv;
      else            v=fabsf(ct-qv);
      ab[row][j]=f2b(v);
    }
    __syncthreads();
    #pragma unroll
    for (int Kt=0;Kt<8;Kt++){
      bf16x8 a0=*(const bf16x8*)&ab[c][Kt*32+quad*8];
      bf16x8 a1=*(const bf16x8*)&ab[16+c][Kt*32+quad*8];
      #pragma unroll
      for (int nt=0;nt<2;nt++){
        int n=(w*2+nt)*16+c;
        bf16x8 bfr=*(const bf16x8*)(W1 + (long)n*1792 + ch*256 + Kt*32 + quad*8);
        acc[0][nt]=mfma16(a0,bfr,acc[0][nt]);
        acc[1][nt]=mfma16(a1,bfr,acc[1][nt]);
      }
    }
  }
  #pragma unroll
  for (int Mt=0;Mt<2;Mt++)
    #pragma unroll
    for (int nt=0;nt<2;nt++)
      #pragma unroll
      for (int r=0;r<4;r++)
        partial[(long)(seq0+Mt*16+quad*4+r)*256 + (w*2+nt)*16+c] = acc[Mt][nt][r];
}

// ---------------------------------------------------------------------------
// Per-episode gate: chunks {mem, ct*mem, |ct-mem|} + partial -> g.
// ---------------------------------------------------------------------------
__global__ __launch_bounds__(512, 1) void k_gate(
    const u16* enc_hi, const u16* enc_lo, const float* mem_f,
    const float* partial, const u16* W1, const float* W2, const float* b2v, float* g)
{
  __shared__ float ctf[32][257];
  __shared__ float mvf[32][257];
  __shared__ u16 ab[32][264];
  __shared__ float pl[32][8];
  int bid=blockIdx.x, tid=threadIdx.x, seq0=bid*32;
  #pragma unroll
  for (int p=0;p<16;p++){
    int i=p*512+tid; int row=i>>8, j=i&255;
    int grow=seq0+row; int b=grow/NSENT;
    ctf[row][j]=b2f(enc_hi[(long)grow*256+j])+b2f(enc_lo[(long)grow*256+j]);
    mvf[row][j]=mem_f[b*256+j];
  }
  const int w=tid>>6, lane=tid&63, c=lane&15, quad=lane>>4;
  f32x4 acc[2][2];
  float w2v[2];
  #pragma unroll
  for (int nt=0;nt<2;nt++){
    int n=(w*2+nt)*16+c;
    w2v[nt]=W2[n];
    #pragma unroll
    for (int Mt=0;Mt<2;Mt++)
      #pragma unroll
      for (int r=0;r<4;r++)
        acc[Mt][nt][r]=partial[(long)(seq0+Mt*16+quad*4+r)*256 + n];
  }
  const int chl[3]={1,4,6};
  for (int ci=0; ci<3; ci++){
    int ch=chl[ci];
    __syncthreads();
    #pragma unroll
    for (int p=0;p<16;p++){
      int i=p*512+tid; int row=i>>8, j=i&255;
      float ct=ctf[row][j], mv=mvf[row][j];
      float v;
      if      (ch==1) v=mv;
      else if (ch==4) v=ct*mv;
      else            v=fabsf(ct-mv);
      ab[row][j]=f2b(v);
    }
    __syncthreads();
    #pragma unroll
    for (int Kt=0;Kt<8;Kt++){
      bf16x8 a0=*(const bf16x8*)&ab[c][Kt*32+quad*8];
      bf16x8 a1=*(const bf16x8*)&ab[16+c][Kt*32+quad*8];
      #pragma unroll
      for (int nt=0;nt<2;nt++){
        int n=(w*2+nt)*16+c;
        bf16x8 bfr=*(const bf16x8*)(W1 + (long)n*1792 + ch*256 + Kt*32 + quad*8);
        acc[0][nt]=mfma16(a0,bfr,acc[0][nt]);
        acc[1][nt]=mfma16(a1,bfr,acc[1][nt]);
      }
    }
  }
  float pm[8];
  #pragma unroll
  for (int i=0;i<8;i++){
    int Mt=i>>2, r=i&3;
    float s=0.f;
    #pragma unroll
    for (int nt=0;nt<2;nt++) s += tanh_(acc[Mt][nt][r])*w2v[nt];
    pm[i]=s;
  }
  #pragma unroll
  for (int off=1;off<16;off<<=1)
    #pragma unroll
    for (int i=0;i<8;i++) pm[i]+=__shfl_xor(pm[i],off,64);
  if (c==0){
    #pragma unroll
    for (int i=0;i<8;i++){ int m=(i>>2)*16+quad*4+(i&3); pl[m][w]=pm[i]; }
  }
  __syncthreads();
  if (tid<32){
    float s=b2v[0];
    #pragma unroll
    for (int ww=0;ww<8;ww++) s+=pl[tid][ww];
    g[seq0+tid]=sigm(s);
  }
}

// ---------------------------------------------------------------------------
// Episodic scan (one episode): 16 WGs x 4 rows; attn_Whh' VGPR-resident (pi),
// in-lane gates, 1 barrier/step, gi_attn LDS double-buffer, g preloaded.
// ---------------------------------------------------------------------------
__global__ __launch_bounds__(512, 2) void k_scan(
    const u16* tWhhP, const float* tBhh,
    const float* gi_attn, const float* g,
    float* mem_f, const u16* mWihB, const u16* mWhhB,
    const float* mbih, const float* mbhh)
{
  __shared__ u16 hb[16][264];
  __shared__ u16 mhi[16][264];
  __shared__ u16 mlo[16][264];
  __shared__ float gia[2][3072];
  __shared__ float gl[4][40];
  __shared__ float gh[4][772];
  __shared__ float gh2[4][772];
  __shared__ float memfl[4][256];
  int bid=blockIdx.x, tid=threadIdx.x, b0=bid*4;
  const int w=tid>>6, lane=tid&63, c=lane&15, quad=lane>>4;
  for (int i=tid;i<16*264;i+=512){ ((u16*)hb)[i]=0; ((u16*)mhi)[i]=0; ((u16*)mlo)[i]=0; }
  for (int i=tid;i<1024;i+=512){
    int m=i>>8, j=i&255;
    float v=mem_f[(b0+m)*256+j]; memfl[m][j]=v;
    u16 hi_=f2b(v); mhi[m][j]=hi_; mlo[m][j]=f2b(v-b2f(hi_));
  }
  if (tid<160){ int m=tid/40, s=tid-m*40; gl[m][s]=g[(b0+m)*40+s]; }
  float biasv[6];
  #pragma unroll
  for (int nt=0;nt<6;nt++) biasv[nt]=tBhh[w*96+nt*16+c];
  uint4 breg[48];
  #pragma unroll
  for (int nt=0;nt<6;nt++)
    #pragma unroll
    for (int Kt=0;Kt<8;Kt++)
      breg[nt*8+Kt] = *(const uint4*)(tWhhP + (w*96+nt*16+c)*256 + Kt*32 + quad*8);
  float hreg[8];
  #pragma unroll
  for (int i=0;i<8;i++) hreg[i]=0.f;
  // staging: 3072 floats = 768 float4; p0: tid<512, p1: tid<256
  int i4a = tid, i4b = 512+tid;
  int ma = i4a/192, ca=(i4a-ma*192)*4;
  int mb = i4b/192, cb=(i4b-mb*192)*4;
  const float* gpa = gi_attn + ((long)(b0+ma)*40)*768 + ca;
  const float* gpb = gi_attn + ((long)(b0+mb)*40)*768 + cb;
  {
    float4 v0=*(const float4*)(gpa);
    *(float4*)&gia[0][i4a*4]=v0;
    if (tid<256){ float4 v1=*(const float4*)(gpb); *(float4*)&gia[0][i4b*4]=v1; }
  }
  __syncthreads();
  int cbuf=0;
  for (int s=0;s<NSENT;s++){
    float4 p0, p1;
    bool pf=(s+1<NSENT);
    if (pf){
      p0=*(const float4*)(gpa + (long)(s+1)*768);
      if (tid<256) p1=*(const float4*)(gpb + (long)(s+1)*768);
    }
    f32x4 acc[6];
    #pragma unroll
    for (int nt=0;nt<6;nt++) acc[nt]=(f32x4){0.f,0.f,0.f,0.f};
    #pragma unroll
    for (int Kt=0;Kt<8;Kt++){
      bf16x8 a=*(const bf16x8*)&hb[c][Kt*32+quad*8];
      #pragma unroll
      for (int nt=0;nt<6;nt++) acc[nt]=mfma16(a,*(const bf16x8*)&breg[nt*8+Kt],acc[nt]);
    }
    if (pf){
      float* gs=&gia[1^cbuf][0];
      *(float4*)(gs+i4a*4)=p0;
      if (tid<256) *(float4*)(gs+i4b*4)=p1;
    }
    if (quad==0){
      const float* ga=&gia[cbuf][0];
      #pragma unroll
      for (int r=0;r<4;r++){
        float gv = gl[r][s];
        const float* gr = ga + r*768 + w*96 + c;
        #pragma unroll
        for (int jj=0;jj<2;jj++){
          int j = w*32+jj*16+c;
          float ir = gr[jj*48];
          float iz = gr[jj*48+16];
          float in_= gr[jj*48+32];
          float hr = acc[jj*3+0][r]+biasv[jj*3+0];
          float hz = acc[jj*3+1][r]+biasv[jj*3+1];
          float hn = acc[jj*3+2][r]+biasv[jj*3+2];
          float rr=sigm(ir+hr), zz=sigm(iz+hz), nn=tanh_(in_+rr*hn);
          float ho=hreg[r*2+jj];
          float hc=(1.f-zz)*nn+zz*ho;
          float hnew=gv*hc+(1.f-gv)*ho;
          hreg[r*2+jj]=hnew;
          hb[r][j]=f2b(hnew);
        }
      }
    }
    __syncthreads();
    cbuf^=1;
  }
  // memory GRU: gi_m = e@mWih^T (+mbih), gh_m = mem(hi/lo)@mWhh^T (+mbhh)
  f32x4 ai[6], ah[6];
  #pragma unroll
  for (int nt=0;nt<6;nt++){ ai[nt]=(f32x4){0.f,0.f,0.f,0.f}; ah[nt]=ai[nt]; }
  #pragma unroll
  for (int Kt=0;Kt<8;Kt++){
    bf16x8 a=*(const bf16x8*)&hb[c][Kt*32+quad*8];
    #pragma unroll
    for (int nt=0;nt<6;nt++){
      bf16x8 bfr=*(const bf16x8*)(mWihB + ((w*6+nt)*16+c)*256 + Kt*32 + quad*8);
      ai[nt]=mfma16(a,bfr,ai[nt]);
    }
  }
  #pragma unroll
  for (int Kt=0;Kt<8;Kt++){
    bf16x8 a=*(const bf16x8*)&mhi[c][Kt*32+quad*8];
    #pragma unroll
    for (int nt=0;nt<6;nt++){
      bf16x8 bfr=*(const bf16x8*)(mWhhB + ((w*6+nt)*16+c)*256 + Kt*32 + quad*8);
      ah[nt]=mfma16(a,bfr,ah[nt]);
    }
  }
  #pragma unroll
  for (int Kt=0;Kt<8;Kt++){
    bf16x8 a=*(const bf16x8*)&mlo[c][Kt*32+quad*8];
    #pragma unroll
    for (int nt=0;nt<6;nt++){
      bf16x8 bfr=*(const bf16x8*)(mWhhB + ((w*6+nt)*16+c)*256 + Kt*32 + quad*8);
      ah[nt]=mfma16(a,bfr,ah[nt]);
    }
  }
  if (quad==0){
    #pragma unroll
    for (int nt=0;nt<6;nt++)
      #pragma unroll
      for (int r=0;r<4;r++){
        gh[r][(w*6+nt)*16+c]=ai[nt][r];
        gh2[r][(w*6+nt)*16+c]=ah[nt][r];
      }
  }
  __syncthreads();
  #pragma unroll
  for (int p=0;p<2;p++){
    int uid=p*512+tid; int m=uid>>8, j=uid&255;
    float ir=gh[m][j]+mbih[j], iz=gh[m][256+j]+mbih[256+j], in_=gh[m][512+j]+mbih[512+j];
    float hr=gh2[m][j]+mbhh[j], hz=gh2[m][256+j]+mbhh[256+j], hn=gh2[m][512+j]+mbhh[512+j];
    float rr=sigm(ir+hr), zz=sigm(iz+hz), nn=tanh_(in_+rr*hn);
    float mo=memfl[m][j];
    mem_f[(b0+m)*256+j]=(1.f-zz)*nn+zz*mo;
  }
}

// ---------------------------------------------------------------------------
// Final head, all fp32.
// ---------------------------------------------------------------------------
__global__ void k_final(const float* mem_f, const float* a1f, const float* a2f,
    const float* W1o, const float* b1o, const float* W2o, const float* b2o, float* outp)
{
  __shared__ float af[768];
  __shared__ float tl[256];
  __shared__ float lg[2];
  int b=blockIdx.x, tid=threadIdx.x;
  af[tid]     = mem_f[b*256+tid];
  af[256+tid] = a1f[b*256+tid];
  af[512+tid] = a2f[b*256+tid];
  __syncthreads();
  float s=b1o[tid];
  const float* wr=W1o + (long)tid*768;
  for (int k=0;k<768;k++) s += af[k]*wr[k];
  tl[tid]=tanh_(s);
  __syncthreads();
  if (tid<2){
    float l=b2o[tid];
    const float* w2=W2o + tid*256;
    for (int k=0;k<256;k++) l += tl[k]*w2[k];
    lg[tid]=l;
  }
  __syncthreads();
  if (tid==0){
    float m=fmaxf(lg[0],lg[1]);
    float e0=__expf(lg[0]-m), e1=__expf(lg[1]-m);
    float inv=1.f/(e0+e1);
    outp[b*2]=e0*inv; outp[b*2+1]=e1*inv;
  }
}

// ---------------------------------------------------------------------------
extern "C" void kernel_launch(void* const* d_in, const int* in_sizes, int n_in,
                              void* d_out, int out_size, void* d_ws, size_t ws_size,
                              hipStream_t stream) {
  const int* c_p   = (const int*)d_in[0];
  const int* c_m   = (const int*)d_in[1];
  const int* q_p   = (const int*)d_in[2];
  const int* q_m   = (const int*)d_in[3];
  const int* a1p   = (const int*)d_in[4];
  const int* a1m   = (const int*)d_in[5];
  const int* a2p   = (const int*)d_in[6];
  const int* a2m   = (const int*)d_in[7];
  const float* embed = (const float*)d_in[8];
  const float* cWih=(const float*)d_in[9],  *cWhh=(const float*)d_in[10], *cbih=(const float*)d_in[11], *cbhh=(const float*)d_in[12];
  const float* qWih=(const float*)d_in[13], *qWhh=(const float*)d_in[14], *qbih=(const float*)d_in[15], *qbhh=(const float*)d_in[16];
  const float* aWih=(const float*)d_in[17], *aWhh=(const float*)d_in[18], *abih=(const float*)d_in[19], *abhh=(const float*)d_in[20];
  const float* tWih=(const float*)d_in[21], *tWhh=(const float*)d_in[22], *tbih=(const float*)d_in[23], *tbhh=(const float*)d_in[24];
  const float* mWih=(const float*)d_in[25], *mWhh=(const float*)d_in[26], *mbih=(const float*)d_in[27], *mbhh=(const float*)d_in[28];
  const float* gW1=(const float*)d_in[29], *gb1=(const float*)d_in[30], *gW2=(const float*)d_in[31], *gb2=(const float*)d_in[32];
  const float* oW1=(const float*)d_in[33], *ob1=(const float*)d_in[34], *oW2=(const float*)d_in[35], *ob2=(const float*)d_in[36];

  char* ws = (char*)d_ws;
  size_t off = 0;
  u16* P0=(u16*)(ws+off); off+=393216;   // cWih'
  u16* P1=(u16*)(ws+off); off+=393216;   // cWhh'
  u16* P2=(u16*)(ws+off); off+=393216;   // qWih'
  u16* P3=(u16*)(ws+off); off+=393216;   // qWhh'
  u16* P4=(u16*)(ws+off); off+=393216;   // aWih'
  u16* P5=(u16*)(ws+off); off+=393216;   // aWhh'
  u16* P6=(u16*)(ws+off); off+=393216;   // tWih'
  u16* P7=(u16*)(ws+off); off+=393216;   // tWhh'
  u16* PmWih=(u16*)(ws+off); off+=393216;
  u16* PmWhh=(u16*)(ws+off); off+=393216;
  u16* PgW1 =(u16*)(ws+off); off+=917504;
  float* B0=(float*)(ws+off); off+=3072;
  float* B1=(float*)(ws+off); off+=3072;
  float* B2=(float*)(ws+off); off+=3072;
  float* B3=(float*)(ws+off); off+=3072;
  float* B4=(float*)(ws+off); off+=3072;
  float* B5=(float*)(ws+off); off+=3072;
  float* B6=(float*)(ws+off); off+=3072;
  float* B7=(float*)(ws+off); off+=3072;
  u16* gi_c =(u16*)(ws+off); off+=(size_t)76800*768*2;
  u16* gi_q =(u16*)(ws+off); off+=(size_t)1280*768*2;
  u16* gi_a1=(u16*)(ws+off); off+=(size_t)768*768*2;
  u16* gi_a2=(u16*)(ws+off); off+=(size_t)768*768*2;
  u16* enc_hi=(u16*)(ws+off); off+=(size_t)SCTX*256*2;
  u16* enc_lo=(u16*)(ws+off); off+=(size_t)SCTX*256*2;
  float* enc_qf =(float*)(ws+off); off+=64*256*4;
  float* enc_a1f=(float*)(ws+off); off+=64*256*4;
  float* enc_a2f=(float*)(ws+off); off+=64*256*4;
  float* mem_f  =(float*)(ws+off); off+=64*256*4;
  float* gi_attn=(float*)(ws+off); off+=(size_t)SCTX*768*4;
  float* partial=(float*)(ws+off); off+=(size_t)SCTX*256*4;
  float* gbuf   =(float*)(ws+off); off+=SCTX*4;

  k_prep<<<4748, 512, 0, stream>>>(cWih,cWhh,qWih,qWhh,aWih,aWhh,tWih,tWhh,mWih,mWhh,gW1,
      cbih,cbhh,qbih,qbhh,abih,abhh,tbih,tbhh,
      P0,P1,P2,P3,P4,P5,P6,P7, PmWih,PmWhh,PgW1,
      B0,B1,B2,B3,B4,B5,B6,B7);

  k_xproj<<<2488, 512, 0, stream>>>(c_p,q_p,a1p,a2p, embed,
      P0,P2,P4, B0,B2,B4, gi_c,gi_q,gi_a1,gi_a2);

  k_enc_scan<<<172, 512, 0, stream>>>(c_m,q_m,a1m,a2m,
      P1,P3,P5, B1,B3,B5, gi_c,gi_q,gi_a1,gi_a2,
      enc_hi,enc_lo, enc_qf,enc_a1f,enc_a2f);

  k_gi<<<41, 512, 0, stream>>>(enc_hi,enc_lo, P6, B6, gi_attn, enc_qf, mem_f);

  k_gatepre<<<80, 512, 0, stream>>>(enc_hi,enc_lo, enc_qf, PgW1, gb1, partial);

  for (int ep=0; ep<3; ep++){
    k_gate<<<80, 512, 0, stream>>>(enc_hi,enc_lo, mem_f, partial, PgW1, gW2, gb2, gbuf);
    k_scan<<<16, 512, 0, stream>>>(P7, B7, gi_attn, gbuf, mem_f, PmWih, PmWhh, mbih, mbhh);
  }

  k_final<<<64, 256, 0, stream>>>(mem_f, enc_a1f, enc_a2f, oW1, ob1, oW2, ob2, (float*)d_out);
}

// Round 5
// 934.210 us; speedup vs baseline: 1.1199x; 1.0251x over previous
//
#include <hip/hip_runtime.h>

typedef unsigned short u16;
typedef __bf16 bf16x8 __attribute__((ext_vector_type(8)));
typedef float f32x4 __attribute__((ext_vector_type(4)));

#define NSENT 40
#define SLEN 30
#define QLEN 20
#define ALEN 12
#define SCTX 2560
#define SLOT 24              // u16 (or fp32) values per lane-slot
#define TP 12288             // 512*24 elements per (block,t) plane

__device__ __forceinline__ float b2f(u16 u){ union{float f; unsigned i;} v; v.i = ((unsigned)u)<<16; return v.f; }
__device__ __forceinline__ u16 f2b(float f){ union{float f; unsigned u;} v; v.f=f; unsigned u=v.u; u += ((u>>16)&1u) + 0x7fffu; return (u16)(u>>16); }
__device__ __forceinline__ float sigm(float x){ return __builtin_amdgcn_rcpf(1.f + __expf(-x)); }
__device__ __forceinline__ float tanh_(float x){
  float a = fminf(fmaxf(2.f*x, -30.f), 30.f);
  float e = __expf(a);
  return 1.f - 2.f*__builtin_amdgcn_rcpf(e + 1.f);
}
__device__ __forceinline__ f32x4 mfma16(bf16x8 a, bf16x8 b, f32x4 c){
  return __builtin_amdgcn_mfma_f32_16x16x32_bf16(a, b, c, 0, 0, 0);
}

// ---------------------------------------------------------------------------
// Prep: pi-permute (n' = g16*48 + gate*16 + c <-> j = gate*256 + g16*16 + c)
// 10 weight mats -> bf16 P0..P9; gW1 plain bf16; 10 pi-permuted fp32 biases.
// ---------------------------------------------------------------------------
__global__ void k_prep(
    const float* cWih, const float* cWhh, const float* qWih, const float* qWhh,
    const float* aWih, const float* aWhh, const float* tWih, const float* tWhh,
    const float* mWih, const float* mWhh, const float* gW1,
    const float* cbih, const float* cbhh, const float* qbih, const float* qbhh,
    const float* abih, const float* abhh, const float* tbih, const float* tbhh,
    const float* mbih, const float* mbhh,
    u16* P0,u16* P1,u16* P2,u16* P3,u16* P4,u16* P5,u16* P6,u16* P7,u16* P8,u16* P9,
    u16* PgW1,
    float* B0,float* B1,float* B2,float* B3,float* B4,float* B5,float* B6,float* B7,
    float* B8,float* B9)
{
  int i = blockIdx.x*512 + threadIdx.x;   // 4751*512 = 2,432,512
  if (i < 1966080){
    int seg = i/196608; int e = i - seg*196608;
    int np = e>>8, k = e&255;
    int g16 = np/48, rem = np - g16*48, gate = rem>>4, cc = rem&15;
    int j = gate*256 + g16*16 + cc;
    const float* S; u16* D;
    switch(seg){
      case 0: S=cWih; D=P0; break; case 1: S=cWhh; D=P1; break;
      case 2: S=qWih; D=P2; break; case 3: S=qWhh; D=P3; break;
      case 4: S=aWih; D=P4; break; case 5: S=aWhh; D=P5; break;
      case 6: S=tWih; D=P6; break; case 7: S=tWhh; D=P7; break;
      case 8: S=mWih; D=P8; break; default: S=mWhh; D=P9; break;
    }
    D[e] = f2b(S[j*256 + k]);
  } else if (i < 2424832){
    int e = i - 1966080;
    PgW1[e] = f2b(gW1[e]);
  } else {
    int e = i - 2424832;                  // 7680 = 10*768
    int seg = e/768; int np = e - seg*768;
    int g16 = np/48, rem = np - g16*48, gate = rem>>4, cc = rem&15;
    int j = gate*256 + g16*16 + cc;
    const float* S; float* D;
    switch(seg){
      case 0: S=cbih; D=B0; break; case 1: S=cbhh; D=B1; break;
      case 2: S=qbih; D=B2; break; case 3: S=qbhh; D=B3; break;
      case 4: S=abih; D=B4; break; case 5: S=abhh; D=B5; break;
      case 6: S=tbih; D=B6; break; case 7: S=tbhh; D=B7; break;
      case 8: S=mbih; D=B8; break; default: S=mbhh; D=B9; break;
    }
    D[np] = S[j];
  }
}

// ---------------------------------------------------------------------------
// x-projections, consumer-packed output. WG = (16-seq block, t-pair).
// Slot layout: gi[(block*T + t)*TP + (w*64+lane)*24 + (r*2+jj)*3+gate]
// ---------------------------------------------------------------------------
__global__ __launch_bounds__(512, 2) void k_xproj(
    const int* c_p, const int* q_p, const int* a1p, const int* a2p,
    const float* embed,
    const u16* cWihP, const u16* qWihP, const u16* aWihP,
    const float* cBih, const float* qBih, const float* aBih,
    u16* gi_c, u16* gi_q, u16* gi_a1, u16* gi_a2)
{
  __shared__ u16 xb[32][264];
  int bid=blockIdx.x, tid=threadIdx.x;
  const int* toks; const u16* W; const float* bias; u16* out; int T, block, t0;
  if (bid < 2400){ toks=c_p; W=cWihP; bias=cBih; out=gi_c; T=SLEN; block=bid/15; t0=(bid-block*15)*2; }
  else if (bid < 2440){ int e=bid-2400; toks=q_p; W=qWihP; bias=qBih; out=gi_q; T=QLEN; block=e/10; t0=(e-block*10)*2; }
  else if (bid < 2464){ int e=bid-2440; toks=a1p; W=aWihP; bias=aBih; out=gi_a1; T=ALEN; block=e/6; t0=(e-block*6)*2; }
  else               { int e=bid-2464; toks=a2p; W=aWihP; bias=aBih; out=gi_a2; T=ALEN; block=e/6; t0=(e-block*6)*2; }
  int seq0 = block*16;
  #pragma unroll
  for (int p=0;p<4;p++){
    int i=p*512+tid; int row=i>>6, f4=i&63;      // row = tp*16+m
    int tp=row>>4, m=row&15;
    int tok = toks[(seq0+m)*T + t0+tp];
    float4 v = *((const float4*)(embed + (long)tok*256) + f4);
    u16* dst = &xb[row][f4*4];
    dst[0]=f2b(v.x); dst[1]=f2b(v.y); dst[2]=f2b(v.z); dst[3]=f2b(v.w);
  }
  const int w=tid>>6, lane=tid&63, c=lane&15, quad=lane>>4;
  f32x4 acc[2][6];
  #pragma unroll
  for (int Mt=0;Mt<2;Mt++)
    #pragma unroll
    for (int nt=0;nt<6;nt++) acc[Mt][nt]=(f32x4){0.f,0.f,0.f,0.f};
  __syncthreads();
  #pragma unroll
  for (int Kt=0;Kt<8;Kt++){
    bf16x8 a0 = *(const bf16x8*)&xb[c][Kt*32+quad*8];
    bf16x8 a1 = *(const bf16x8*)&xb[16+c][Kt*32+quad*8];
    #pragma unroll
    for (int nt=0;nt<6;nt++){
      bf16x8 bfr = *(const bf16x8*)(W + (w*96+nt*16+c)*256 + Kt*32 + quad*8);
      acc[0][nt]=mfma16(a0,bfr,acc[0][nt]);
      acc[1][nt]=mfma16(a1,bfr,acc[1][nt]);
    }
  }
  float biasv[6];
  #pragma unroll
  for (int nt=0;nt<6;nt++) biasv[nt]=bias[w*96+nt*16+c];
  #pragma unroll
  for (int tp=0;tp<2;tp++){
    unsigned d[12];
    #pragma unroll
    for (int k=0;k<12;k++){
      int i0=2*k, i1=2*k+1;
      int r0=i0/6, re0=i0%6, jj0=re0/3, g0=re0%3;
      int r1=i1/6, re1=i1%6, jj1=re1/3, g1=re1%3;
      unsigned lo=f2b(acc[tp][jj0*3+g0][r0]+biasv[jj0*3+g0]);
      unsigned hi=f2b(acc[tp][jj1*3+g1][r1]+biasv[jj1*3+g1]);
      d[k] = lo | (hi<<16);
    }
    u16* dst = out + ((long)(block*T + t0+tp))*TP + (w*64+lane)*SLOT;
    *(uint4*)(dst)    = *(uint4*)&d[0];
    *(uint4*)(dst+8)  = *(uint4*)&d[4];
    *(uint4*)(dst+16) = *(uint4*)&d[8];
  }
}

// ---------------------------------------------------------------------------
// Recurrent encoder scans: packed gi via 3 per-lane uint4 loads, prefetch-1,
// no gi LDS. 172 WGs x 16 seqs, 1 barrier/step.
// ---------------------------------------------------------------------------
__global__ __launch_bounds__(512, 2) void k_enc_scan(
    const int* c_mask, const int* q_mask, const int* a1m, const int* a2m,
    const u16* cWhhP, const u16* qWhhP, const u16* aWhhP,
    const float* cBhh, const float* qBhh, const float* aBhh,
    const u16* gi_c, const u16* gi_q, const u16* gi_a1, const u16* gi_a2,
    u16* enc_hi, u16* enc_lo, float* enc_qf, float* enc_a1f, float* enc_a2f)
{
  __shared__ u16 hhi[16][264];
  __shared__ u16 hlo[16][264];
  __shared__ int idxs[16];
  int bid=blockIdx.x, tid=threadIdx.x;
  const int* msk; const u16* W; const float* bhh; const u16* gi; int T, seq0, mode;
  u16 *ohi=0, *olo=0; float* of=0;
  if (bid<160){ msk=c_mask; W=cWhhP; bhh=cBhh; gi=gi_c+(long)bid*SLEN*TP; T=SLEN; seq0=bid*16; mode=0; ohi=enc_hi; olo=enc_lo; }
  else if (bid<164){ int e=bid-160; msk=q_mask; W=qWhhP; bhh=qBhh; gi=gi_q+(long)e*QLEN*TP; T=QLEN; seq0=e*16; mode=1; of=enc_qf; }
  else if (bid<168){ int e=bid-164; msk=a1m; W=aWhhP; bhh=aBhh; gi=gi_a1+(long)e*ALEN*TP; T=ALEN; seq0=e*16; mode=1; of=enc_a1f; }
  else             { int e=bid-168; msk=a2m; W=aWhhP; bhh=aBhh; gi=gi_a2+(long)e*ALEN*TP; T=ALEN; seq0=e*16; mode=1; of=enc_a2f; }
  if (tid<16){
    int len=0; const int* mr=msk+(seq0+tid)*T;
    for (int t=0;t<T;t++) len += (mr[t]==0);
    int id=len-1; if(id<0)id=0; if(id>T-1)id=T-1; idxs[tid]=id;
  }
  for (int i=tid;i<16*264;i+=512){ ((u16*)hhi)[i]=0; ((u16*)hlo)[i]=0; }
  const int w=tid>>6, lane=tid&63, c=lane&15, quad=lane>>4;
  float biasv[6];
  #pragma unroll
  for (int nt=0;nt<6;nt++) biasv[nt]=bhh[w*96+nt*16+c];
  uint4 breg[48];
  #pragma unroll
  for (int nt=0;nt<6;nt++)
    #pragma unroll
    for (int Kt=0;Kt<8;Kt++)
      breg[nt*8+Kt] = *(const uint4*)(W + (w*96+nt*16+c)*256 + Kt*32 + quad*8);
  float hreg[8];
  #pragma unroll
  for (int i=0;i<8;i++) hreg[i]=0.f;
  const u16* gp = gi + (w*64+lane)*SLOT;
  uint4 pA0=*(const uint4*)(gp), pA1=*(const uint4*)(gp+8), pA2=*(const uint4*)(gp+16);
  __syncthreads();
  int idxr[4];
  #pragma unroll
  for (int r=0;r<4;r++) idxr[r]=idxs[quad*4+r];

  for (int t=0;t<T;t++){
    uint4 pB0,pB1,pB2;
    bool pf=(t+1<T);
    if (pf){
      const u16* gn = gp + (long)(t+1)*TP;
      pB0=*(const uint4*)(gn); pB1=*(const uint4*)(gn+8); pB2=*(const uint4*)(gn+16);
    }
    f32x4 acc[6];
    #pragma unroll
    for (int nt=0;nt<6;nt++) acc[nt]=(f32x4){0.f,0.f,0.f,0.f};
    #pragma unroll
    for (int Kt=0;Kt<8;Kt++){
      bf16x8 a=*(const bf16x8*)&hhi[c][Kt*32+quad*8];
      #pragma unroll
      for (int nt=0;nt<6;nt++) acc[nt]=mfma16(a,*(const bf16x8*)&breg[nt*8+Kt],acc[nt]);
    }
    #pragma unroll
    for (int Kt=0;Kt<8;Kt++){
      bf16x8 a=*(const bf16x8*)&hlo[c][Kt*32+quad*8];
      #pragma unroll
      for (int nt=0;nt<6;nt++) acc[nt]=mfma16(a,*(const bf16x8*)&breg[nt*8+Kt],acc[nt]);
    }
    unsigned pd[12];
    *(uint4*)&pd[0]=pA0; *(uint4*)&pd[4]=pA1; *(uint4*)&pd[8]=pA2;
    #pragma unroll
    for (int r=0;r<4;r++){
      int m=quad*4+r;
      #pragma unroll
      for (int jj=0;jj<2;jj++){
        int j=w*32+jj*16+c;
        int ib=(r*2+jj)*3;
        float ir = b2f((u16)((pd[ib>>1]     >> ((ib&1)*16)) & 0xffffu));
        float iz = b2f((u16)((pd[(ib+1)>>1] >> (((ib+1)&1)*16)) & 0xffffu));
        float in_= b2f((u16)((pd[(ib+2)>>1] >> (((ib+2)&1)*16)) & 0xffffu));
        float hr=acc[jj*3+0][r]+biasv[jj*3+0];
        float hz=acc[jj*3+1][r]+biasv[jj*3+1];
        float hn=acc[jj*3+2][r]+biasv[jj*3+2];
        float rr=sigm(ir+hr), zz=sigm(iz+hz), nn=tanh_(in_+rr*hn);
        float ho=hreg[r*2+jj];
        float hnew=(1.f-zz)*nn+zz*ho;
        hreg[r*2+jj]=hnew;
        u16 hi_=f2b(hnew); u16 lo_=f2b(hnew-b2f(hi_));
        hhi[m][j]=hi_; hlo[m][j]=lo_;
        if (t==idxr[r]){
          long o=(long)(seq0+m)*256+j;
          if (mode==0){ ohi[o]=hi_; olo[o]=lo_; }
          else of[o]=hnew;
        }
      }
    }
    __syncthreads();
    pA0=pB0; pA1=pB1; pA2=pB2;
  }
}

// ---------------------------------------------------------------------------
// gi_attn packed fp32: WG = (b-block of 16, sentence s). 160 WGs + init WG.
// Slot: gi_attn[(bblk*40+s)*TP + (w*64+lane)*24 + (r*2+jj)*3+gate]
// ---------------------------------------------------------------------------
__global__ __launch_bounds__(512, 2) void k_gi(
    const u16* enc_hi, const u16* enc_lo, const u16* tWihP, const float* tBih,
    float* gi_attn, const float* enc_qf, float* mem_f)
{
  int bid=blockIdx.x, tid=threadIdx.x;
  if (bid==160){ for (int i=tid;i<64*256;i+=512) mem_f[i]=enc_qf[i]; return; }
  __shared__ u16 ahi[16][264];
  __shared__ u16 alo[16][264];
  int bblk=bid/40, s=bid-bblk*40, b0=bblk*16;
  {
    int row=tid>>5, ch=tid&31;
    long seq=(long)(b0+row)*NSENT + s;
    *(uint4*)((char*)&ahi[row][0]+ch*16) = *((const uint4*)(enc_hi+seq*256)+ch);
    *(uint4*)((char*)&alo[row][0]+ch*16) = *((const uint4*)(enc_lo+seq*256)+ch);
  }
  const int w=tid>>6, lane=tid&63, c=lane&15, quad=lane>>4;
  f32x4 acc[6];
  #pragma unroll
  for (int nt=0;nt<6;nt++) acc[nt]=(f32x4){0.f,0.f,0.f,0.f};
  __syncthreads();
  #pragma unroll
  for (int Kt=0;Kt<8;Kt++){
    bf16x8 a=*(const bf16x8*)&ahi[c][Kt*32+quad*8];
    #pragma unroll
    for (int nt=0;nt<6;nt++){
      bf16x8 bfr=*(const bf16x8*)(tWihP + (w*96+nt*16+c)*256 + Kt*32 + quad*8);
      acc[nt]=mfma16(a,bfr,acc[nt]);
    }
  }
  #pragma unroll
  for (int Kt=0;Kt<8;Kt++){
    bf16x8 a=*(const bf16x8*)&alo[c][Kt*32+quad*8];
    #pragma unroll
    for (int nt=0;nt<6;nt++){
      bf16x8 bfr=*(const bf16x8*)(tWihP + (w*96+nt*16+c)*256 + Kt*32 + quad*8);
      acc[nt]=mfma16(a,bfr,acc[nt]);
    }
  }
  float biasv[6];
  #pragma unroll
  for (int nt=0;nt<6;nt++) biasv[nt]=tBih[w*96+nt*16+c];
  float* dst = gi_attn + ((long)(bblk*40+s))*TP + (w*64+lane)*SLOT;
  #pragma unroll
  for (int d=0;d<6;d++){
    float4 v;
    #pragma unroll
    for (int e=0;e<4;e++){
      int idx=4*d+e;
      int r=idx/6, rem=idx%6, jj=rem/3, g=rem%3;
      ((float*)&v)[e]=acc[jj*3+g][r]+biasv[jj*3+g];
    }
    *(float4*)(dst+4*d)=v;
  }
}

// ---------------------------------------------------------------------------
// Gate precompute (episode-invariant chunks {ct,q,ct*q,|ct-q|}).
// ---------------------------------------------------------------------------
__global__ __launch_bounds__(512, 1) void k_gatepre(
    const u16* enc_hi, const u16* enc_lo, const float* enc_qf,
    const u16* W1, const float* b1, float* partial)
{
  __shared__ float ctf[32][257];
  __shared__ float qvf[32][257];
  __shared__ u16 ab[32][264];
  int bid=blockIdx.x, tid=threadIdx.x, seq0=bid*32;
  #pragma unroll
  for (int p=0;p<16;p++){
    int i=p*512+tid; int row=i>>8, j=i&255;
    int grow=seq0+row; int b=grow/NSENT;
    ctf[row][j]=b2f(enc_hi[(long)grow*256+j])+b2f(enc_lo[(long)grow*256+j]);
    qvf[row][j]=enc_qf[b*256+j];
  }
  const int w=tid>>6, lane=tid&63, c=lane&15, quad=lane>>4;
  f32x4 acc[2][2];
  #pragma unroll
  for (int nt=0;nt<2;nt++){
    float bv=b1[(w*2+nt)*16+c];
    acc[0][nt]=(f32x4){bv,bv,bv,bv}; acc[1][nt]=acc[0][nt];
  }
  const int chl[4]={0,2,3,5};
  for (int ci=0; ci<4; ci++){
    int ch=chl[ci];
    __syncthreads();
    #pragma unroll
    for (int p=0;p<16;p++){
      int i=p*512+tid; int row=i>>8, j=i&255;
      float ct=ctf[row][j], qv=qvf[row][j];
      float v;
      if      (ch==0) v=ct;
      else if (ch==2) v=qv;
      else if (ch==3) v=ct*qv;
      else            v=fabsf(ct-qv);
      ab[row][j]=f2b(v);
    }
    __syncthreads();
    #pragma unroll
    for (int Kt=0;Kt<8;Kt++){
      bf16x8 a0=*(const bf16x8*)&ab[c][Kt*32+quad*8];
      bf16x8 a1=*(const bf16x8*)&ab[16+c][Kt*32+quad*8];
      #pragma unroll
      for (int nt=0;nt<2;nt++){
        int n=(w*2+nt)*16+c;
        bf16x8 bfr=*(const bf16x8*)(W1 + (long)n*1792 + ch*256 + Kt*32 + quad*8);
        acc[0][nt]=mfma16(a0,bfr,acc[0][nt]);
        acc[1][nt]=mfma16(a1,bfr,acc[1][nt]);
      }
    }
  }
  #pragma unroll
  for (int Mt=0;Mt<2;Mt++)
    #pragma unroll
    for (int nt=0;nt<2;nt++)
      #pragma unroll
      for (int r=0;r<4;r++)
        partial[(long)(seq0+Mt*16+quad*4+r)*256 + (w*2+nt)*16+c] = acc[Mt][nt][r];
}

// ---------------------------------------------------------------------------
// Per-episode gate: chunks {mem, ct*mem, |ct-mem|} + partial -> g.
// ---------------------------------------------------------------------------
__global__ __launch_bounds__(512, 1) void k_gate(
    const u16* enc_hi, const u16* enc_lo, const float* mem_f,
    const float* partial, const u16* W1, const float* W2, const float* b2v, float* g)
{
  __shared__ float ctf[32][257];
  __shared__ float mvf[32][257];
  __shared__ u16 ab[32][264];
  __shared__ float pl[32][8];
  int bid=blockIdx.x, tid=threadIdx.x, seq0=bid*32;
  #pragma unroll
  for (int p=0;p<16;p++){
    int i=p*512+tid; int row=i>>8, j=i&255;
    int grow=seq0+row; int b=grow/NSENT;
    ctf[row][j]=b2f(enc_hi[(long)grow*256+j])+b2f(enc_lo[(long)grow*256+j]);
    mvf[row][j]=mem_f[b*256+j];
  }
  const int w=tid>>6, lane=tid&63, c=lane&15, quad=lane>>4;
  f32x4 acc[2][2];
  float w2v[2];
  #pragma unroll
  for (int nt=0;nt<2;nt++){
    int n=(w*2+nt)*16+c;
    w2v[nt]=W2[n];
    #pragma unroll
    for (int Mt=0;Mt<2;Mt++)
      #pragma unroll
      for (int r=0;r<4;r++)
        acc[Mt][nt][r]=partial[(long)(seq0+Mt*16+quad*4+r)*256 + n];
  }
  const int chl[3]={1,4,6};
  for (int ci=0; ci<3; ci++){
    int ch=chl[ci];
    __syncthreads();
    #pragma unroll
    for (int p=0;p<16;p++){
      int i=p*512+tid; int row=i>>8, j=i&255;
      float ct=ctf[row][j], mv=mvf[row][j];
      float v;
      if      (ch==1) v=mv;
      else if (ch==4) v=ct*mv;
      else            v=fabsf(ct-mv);
      ab[row][j]=f2b(v);
    }
    __syncthreads();
    #pragma unroll
    for (int Kt=0;Kt<8;Kt++){
      bf16x8 a0=*(const bf16x8*)&ab[c][Kt*32+quad*8];
      bf16x8 a1=*(const bf16x8*)&ab[16+c][Kt*32+quad*8];
      #pragma unroll
      for (int nt=0;nt<2;nt++){
        int n=(w*2+nt)*16+c;
        bf16x8 bfr=*(const bf16x8*)(W1 + (long)n*1792 + ch*256 + Kt*32 + quad*8);
        acc[0][nt]=mfma16(a0,bfr,acc[0][nt]);
        acc[1][nt]=mfma16(a1,bfr,acc[1][nt]);
      }
    }
  }
  float pm[8];
  #pragma unroll
  for (int i=0;i<8;i++){
    int Mt=i>>2, r=i&3;
    float s=0.f;
    #pragma unroll
    for (int nt=0;nt<2;nt++) s += tanh_(acc[Mt][nt][r])*w2v[nt];
    pm[i]=s;
  }
  #pragma unroll
  for (int off=1;off<16;off<<=1)
    #pragma unroll
    for (int i=0;i<8;i++) pm[i]+=__shfl_xor(pm[i],off,64);
  if (c==0){
    #pragma unroll
    for (int i=0;i<8;i++){ int m=(i>>2)*16+quad*4+(i&3); pl[m][w]=pm[i]; }
  }
  __syncthreads();
  if (tid<32){
    float s=b2v[0];
    #pragma unroll
    for (int ww=0;ww<8;ww++) s+=pl[tid][ww];
    g[seq0+tid]=sigm(s);
  }
}

// ---------------------------------------------------------------------------
// Episodic scan: 4 WGs x 16 batch rows; attn_Whh' VGPR-resident; packed
// gi_attn prefetch; all-lane elementwise; pi mem-GRU tail (lane-local).
// ---------------------------------------------------------------------------
__global__ __launch_bounds__(512, 2) void k_scan(
    const u16* tWhhP, const float* tBhh,
    const float* gi_attn, const float* g,
    float* mem_f, const u16* mWihP, const u16* mWhhP,
    const float* mBih, const float* mBhh)
{
  __shared__ u16 hb[16][264];
  __shared__ u16 mhi[16][264];
  __shared__ u16 mlo[16][264];
  __shared__ float memfl[16][256];
  __shared__ float gl[16][40];
  int bid=blockIdx.x, tid=threadIdx.x, b0=bid*16;
  const int w=tid>>6, lane=tid&63, c=lane&15, quad=lane>>4;
  for (int i=tid;i<16*264;i+=512){ ((u16*)hb)[i]=0; }
  for (int i=tid;i<4096;i+=512){
    int m=i>>8, j=i&255;
    float v=mem_f[(b0+m)*256+j]; memfl[m][j]=v;
    u16 hi_=f2b(v); mhi[m][j]=hi_; mlo[m][j]=f2b(v-b2f(hi_));
  }
  for (int i=tid;i<640;i+=512){ int m=i/40, s=i-m*40; gl[m][s]=g[(b0+m)*40+s]; }
  float biasv[6];
  #pragma unroll
  for (int nt=0;nt<6;nt++) biasv[nt]=tBhh[w*96+nt*16+c];
  uint4 breg[48];
  #pragma unroll
  for (int nt=0;nt<6;nt++)
    #pragma unroll
    for (int Kt=0;Kt<8;Kt++)
      breg[nt*8+Kt] = *(const uint4*)(tWhhP + (w*96+nt*16+c)*256 + Kt*32 + quad*8);
  float hreg[8];
  #pragma unroll
  for (int i=0;i<8;i++) hreg[i]=0.f;
  const float* gp = gi_attn + ((long)bid*NSENT)*TP + (w*64+lane)*SLOT;
  float4 pA[6];
  #pragma unroll
  for (int d=0;d<6;d++) pA[d]=*(const float4*)(gp+4*d);
  __syncthreads();

  for (int s=0;s<NSENT;s++){
    float4 pB[6];
    bool pf=(s+1<NSENT);
    if (pf){
      const float* gn = gp + (long)(s+1)*TP;
      #pragma unroll
      for (int d=0;d<6;d++) pB[d]=*(const float4*)(gn+4*d);
    }
    f32x4 acc[6];
    #pragma unroll
    for (int nt=0;nt<6;nt++) acc[nt]=(f32x4){0.f,0.f,0.f,0.f};
    #pragma unroll
    for (int Kt=0;Kt<8;Kt++){
      bf16x8 a=*(const bf16x8*)&hb[c][Kt*32+quad*8];
      #pragma unroll
      for (int nt=0;nt<6;nt++) acc[nt]=mfma16(a,*(const bf16x8*)&breg[nt*8+Kt],acc[nt]);
    }
    const float* pf32 = (const float*)&pA[0];
    #pragma unroll
    for (int r=0;r<4;r++){
      int m=quad*4+r;
      float gv = gl[m][s];
      #pragma unroll
      for (int jj=0;jj<2;jj++){
        int j=w*32+jj*16+c;
        int ib=(r*2+jj)*3;
        float ir=pf32[ib], iz=pf32[ib+1], in_=pf32[ib+2];
        float hr=acc[jj*3+0][r]+biasv[jj*3+0];
        float hz=acc[jj*3+1][r]+biasv[jj*3+1];
        float hn=acc[jj*3+2][r]+biasv[jj*3+2];
        float rr=sigm(ir+hr), zz=sigm(iz+hz), nn=tanh_(in_+rr*hn);
        float ho=hreg[r*2+jj];
        float hc=(1.f-zz)*nn+zz*ho;
        float hnew=gv*hc+(1.f-gv)*ho;
        hreg[r*2+jj]=hnew;
        hb[m][j]=f2b(hnew);
      }
    }
    __syncthreads();
    #pragma unroll
    for (int d=0;d<6;d++) pA[d]=pB[d];
  }
  // memory GRU, pi layout: ai = e@mWih'^T, ah = mem(hi+lo)@mWhh'^T
  f32x4 ai[6], ah[6];
  #pragma unroll
  for (int nt=0;nt<6;nt++){ ai[nt]=(f32x4){0.f,0.f,0.f,0.f}; ah[nt]=ai[nt]; }
  #pragma unroll
  for (int Kt=0;Kt<8;Kt++){
    bf16x8 a=*(const bf16x8*)&hb[c][Kt*32+quad*8];
    #pragma unroll
    for (int nt=0;nt<6;nt++){
      bf16x8 bfr=*(const bf16x8*)(mWihP + (w*96+nt*16+c)*256 + Kt*32 + quad*8);
      ai[nt]=mfma16(a,bfr,ai[nt]);
    }
  }
  #pragma unroll
  for (int Kt=0;Kt<8;Kt++){
    bf16x8 a=*(const bf16x8*)&mhi[c][Kt*32+quad*8];
    #pragma unroll
    for (int nt=0;nt<6;nt++){
      bf16x8 bfr=*(const bf16x8*)(mWhhP + (w*96+nt*16+c)*256 + Kt*32 + quad*8);
      ah[nt]=mfma16(a,bfr,ah[nt]);
    }
  }
  #pragma unroll
  for (int Kt=0;Kt<8;Kt++){
    bf16x8 a=*(const bf16x8*)&mlo[c][Kt*32+quad*8];
    #pragma unroll
    for (int nt=0;nt<6;nt++){
      bf16x8 bfr=*(const bf16x8*)(mWhhP + (w*96+nt*16+c)*256 + Kt*32 + quad*8);
      ah[nt]=mfma16(a,bfr,ah[nt]);
    }
  }
  float bih6[6], bhh6[6];
  #pragma unroll
  for (int nt=0;nt<6;nt++){ bih6[nt]=mBih[w*96+nt*16+c]; bhh6[nt]=mBhh[w*96+nt*16+c]; }
  #pragma unroll
  for (int r=0;r<4;r++){
    int m=quad*4+r;
    #pragma unroll
    for (int jj=0;jj<2;jj++){
      int j=w*32+jj*16+c;
      float ir=ai[jj*3+0][r]+bih6[jj*3+0];
      float iz=ai[jj*3+1][r]+bih6[jj*3+1];
      float in_=ai[jj*3+2][r]+bih6[jj*3+2];
      float hr=ah[jj*3+0][r]+bhh6[jj*3+0];
      float hz=ah[jj*3+1][r]+bhh6[jj*3+1];
      float hn=ah[jj*3+2][r]+bhh6[jj*3+2];
      float rr=sigm(ir+hr), zz=sigm(iz+hz), nn=tanh_(in_+rr*hn);
      float mo=memfl[m][j];
      mem_f[(b0+m)*256+j]=(1.f-zz)*nn+zz*mo;
    }
  }
}

// ---------------------------------------------------------------------------
// Final head, all fp32.
// ---------------------------------------------------------------------------
__global__ void k_final(const float* mem_f, const float* a1f, const float* a2f,
    const float* W1o, const float* b1o, const float* W2o, const float* b2o, float* outp)
{
  __shared__ float af[768];
  __shared__ float tl[256];
  __shared__ float lg[2];
  int b=blockIdx.x, tid=threadIdx.x;
  af[tid]     = mem_f[b*256+tid];
  af[256+tid] = a1f[b*256+tid];
  af[512+tid] = a2f[b*256+tid];
  __syncthreads();
  float s=b1o[tid];
  const float* wr=W1o + (long)tid*768;
  for (int k=0;k<768;k++) s += af[k]*wr[k];
  tl[tid]=tanh_(s);
  __syncthreads();
  if (tid<2){
    float l=b2o[tid];
    const float* w2=W2o + tid*256;
    for (int k=0;k<256;k++) l += tl[k]*w2[k];
    lg[tid]=l;
  }
  __syncthreads();
  if (tid==0){
    float m=fmaxf(lg[0],lg[1]);
    float e0=__expf(lg[0]-m), e1=__expf(lg[1]-m);
    float inv=1.f/(e0+e1);
    outp[b*2]=e0*inv; outp[b*2+1]=e1*inv;
  }
}

// ---------------------------------------------------------------------------
extern "C" void kernel_launch(void* const* d_in, const int* in_sizes, int n_in,
                              void* d_out, int out_size, void* d_ws, size_t ws_size,
                              hipStream_t stream) {
  const int* c_p   = (const int*)d_in[0];
  const int* c_m   = (const int*)d_in[1];
  const int* q_p   = (const int*)d_in[2];
  const int* q_m   = (const int*)d_in[3];
  const int* a1p   = (const int*)d_in[4];
  const int* a1m   = (const int*)d_in[5];
  const int* a2p   = (const int*)d_in[6];
  const int* a2m   = (const int*)d_in[7];
  const float* embed = (const float*)d_in[8];
  const float* cWih=(const float*)d_in[9],  *cWhh=(const float*)d_in[10], *cbih=(const float*)d_in[11], *cbhh=(const float*)d_in[12];
  const float* qWih=(const float*)d_in[13], *qWhh=(const float*)d_in[14], *qbih=(const float*)d_in[15], *qbhh=(const float*)d_in[16];
  const float* aWih=(const float*)d_in[17], *aWhh=(const float*)d_in[18], *abih=(const float*)d_in[19], *abhh=(const float*)d_in[20];
  const float* tWih=(const float*)d_in[21], *tWhh=(const float*)d_in[22], *tbih=(const float*)d_in[23], *tbhh=(const float*)d_in[24];
  const float* mWih=(const float*)d_in[25], *mWhh=(const float*)d_in[26], *mbih=(const float*)d_in[27], *mbhh=(const float*)d_in[28];
  const float* gW1=(const float*)d_in[29], *gb1=(const float*)d_in[30], *gW2=(const float*)d_in[31], *gb2=(const float*)d_in[32];
  const float* oW1=(const float*)d_in[33], *ob1=(const float*)d_in[34], *oW2=(const float*)d_in[35], *ob2=(const float*)d_in[36];

  char* ws = (char*)d_ws;
  size_t off = 0;
  u16* P[10];
  for (int i=0;i<10;i++){ P[i]=(u16*)(ws+off); off+=393216; }
  u16* PgW1 =(u16*)(ws+off); off+=917504;
  float* B[10];
  for (int i=0;i<10;i++){ B[i]=(float*)(ws+off); off+=3072; }
  u16* gi_c =(u16*)(ws+off); off+=(size_t)160*SLEN*TP*2;   // 118 MB
  u16* gi_q =(u16*)(ws+off); off+=(size_t)4*QLEN*TP*2;
  u16* gi_a1=(u16*)(ws+off); off+=(size_t)4*ALEN*TP*2;
  u16* gi_a2=(u16*)(ws+off); off+=(size_t)4*ALEN*TP*2;
  u16* enc_hi=(u16*)(ws+off); off+=(size_t)SCTX*256*2;
  u16* enc_lo=(u16*)(ws+off); off+=(size_t)SCTX*256*2;
  float* enc_qf =(float*)(ws+off); off+=64*256*4;
  float* enc_a1f=(float*)(ws+off); off+=64*256*4;
  float* enc_a2f=(float*)(ws+off); off+=64*256*4;
  float* mem_f  =(float*)(ws+off); off+=64*256*4;
  float* gi_attn=(float*)(ws+off); off+=(size_t)160*TP*4;  // 7.9 MB
  float* partial=(float*)(ws+off); off+=(size_t)SCTX*256*4;
  float* gbuf   =(float*)(ws+off); off+=SCTX*4;

  k_prep<<<4751, 512, 0, stream>>>(cWih,cWhh,qWih,qWhh,aWih,aWhh,tWih,tWhh,mWih,mWhh,gW1,
      cbih,cbhh,qbih,qbhh,abih,abhh,tbih,tbhh,mbih,mbhh,
      P[0],P[1],P[2],P[3],P[4],P[5],P[6],P[7],P[8],P[9], PgW1,
      B[0],B[1],B[2],B[3],B[4],B[5],B[6],B[7],B[8],B[9]);

  k_xproj<<<2488, 512, 0, stream>>>(c_p,q_p,a1p,a2p, embed,
      P[0],P[2],P[4], B[0],B[2],B[4], gi_c,gi_q,gi_a1,gi_a2);

  k_enc_scan<<<172, 512, 0, stream>>>(c_m,q_m,a1m,a2m,
      P[1],P[3],P[5], B[1],B[3],B[5], gi_c,gi_q,gi_a1,gi_a2,
      enc_hi,enc_lo, enc_qf,enc_a1f,enc_a2f);

  k_gi<<<161, 512, 0, stream>>>(enc_hi,enc_lo, P[6], B[6], gi_attn, enc_qf, mem_f);

  k_gatepre<<<80, 512, 0, stream>>>(enc_hi,enc_lo, enc_qf, PgW1, gb1, partial);

  for (int ep=0; ep<3; ep++){
    k_gate<<<80, 512, 0, stream>>>(enc_hi,enc_lo, mem_f, partial, PgW1, gW2, gb2, gbuf);
    k_scan<<<4, 512, 0, stream>>>(P[7], B[7], gi_attn, gbuf, mem_f, P[8], P[9], B[8], B[9]);
  }

  k_final<<<64, 256, 0, stream>>>(mem_f, enc_a1f, enc_a2f, oW1, ob1, oW2, ob2, (float*)d_out);
}